// Round 1
// baseline (15446.631 us; speedup 1.0000x reference)
//
#include <hip/hip_runtime.h>
#include <hip/hip_bf16.h>
#include <math.h>

#define VOCABN 256
#define EMBN   384
#define DM     512
#define DI     1024
#define DSTATE 16
#define DCONVN 4
#define DTRANK 32
#define NLAYER 8
#define BBATCH 2
#define LSEQ   2048
#define MROWS  (BBATCH*LSEQ)   // 4096

// ---------------- weight transpose: w[co][ci][k] -> wt[k][ci][co] ----------------
template<int CI, int CK>
__global__ void transpose_w_kernel(const float* __restrict__ w, float* __restrict__ wt) {
    int idx = blockIdx.x * 256 + threadIdx.x;
    int total = 512 * CI * CK;
    if (idx >= total) return;
    int k  = idx % CK;
    int ci = (idx / CK) % CI;
    int co = idx / (CK * CI);
    wt[(k * CI + ci) * 512 + co] = w[idx];
}

// ---------------- embedding gather ----------------
__global__ void embed_kernel(const int* __restrict__ tok, const float* __restrict__ emb,
                             float* __restrict__ x0) {
    int idx = blockIdx.x * 256 + threadIdx.x;   // over MROWS*EMBN
    int c = idx % EMBN;
    int t = idx / EMBN;
    x0[idx] = emb[tok[t] * EMBN + c];
}

__device__ __forceinline__ float gelu_exact(float x) {
    return 0.5f * x * (1.f + erff(x * 0.70710678118654752f));
}

// ---------------- conv over time + bias + GELU ----------------
// x: (B, L, CI) row-major; wt: (CK, CI, 512); out: (B, L, 512)
// block: 64 t x 64 co, 256 threads (wave = 64 co lanes, row = t-subblock of 16)
template<int CI, int CK, int PAD, int CICHUNK>
__global__ __launch_bounds__(256) void conv_gelu_kernel(
    const float* __restrict__ x, const float* __restrict__ wt,
    const float* __restrict__ bias, float* __restrict__ out)
{
    const int t0   = blockIdx.x * 64;          // global row base (b*L + t)
    const int co0  = blockIdx.y * 64;
    const int lane = threadIdx.x & 63;
    const int row  = threadIdx.x >> 6;         // 0..3
    const int co   = co0 + lane;
    const int b    = t0 / LSEQ;
    const int tb   = t0 - b * LSEQ;

    const int W = 64 + CK - 1;                 // staged window width
    __shared__ float xs[CICHUNK][69];          // pitch 69 kills write conflicts

    float acc[16];
#pragma unroll
    for (int i = 0; i < 16; i++) acc[i] = 0.f;

    for (int ci0 = 0; ci0 < CI; ci0 += CICHUNK) {
        // stage x window (transposed) into LDS
        for (int f = threadIdx.x; f < W * CICHUNK; f += 256) {
            int tl = f / CICHUNK;
            int cc = f % CICHUNK;
            int t  = tb - PAD + tl;
            float v = 0.f;
            if (t >= 0 && t < LSEQ) v = x[(b * LSEQ + t) * CI + ci0 + cc];
            xs[cc][tl] = v;
        }
        __syncthreads();

        for (int cc = 0; cc < CICHUNK; cc++) {
            float xv[16 + CK - 1];
#pragma unroll
            for (int j = 0; j < 16 + CK - 1; j++) xv[j] = xs[cc][row * 16 + j];
            float wv[CK];
#pragma unroll
            for (int k = 0; k < CK; k++) wv[k] = wt[(k * CI + ci0 + cc) * 512 + co];
#pragma unroll
            for (int k = 0; k < CK; k++)
#pragma unroll
                for (int i = 0; i < 16; i++) acc[i] = fmaf(xv[i + k], wv[k], acc[i]);
        }
        __syncthreads();
    }

    float bv = bias[co];
#pragma unroll
    for (int i = 0; i < 16; i++) {
        int r = t0 + row * 16 + i;
        out[r * 512 + co] = gelu_exact(acc[i] + bv);
    }
}

// ---------------- layernorm over 512, optional +pos_emb ----------------
template<bool ADDPOS>
__global__ __launch_bounds__(256) void ln_kernel(
    const float* __restrict__ in, const float* __restrict__ g, const float* __restrict__ bb,
    const float* __restrict__ pos, float* __restrict__ out)
{
    int row  = blockIdx.x * 4 + (threadIdx.x >> 6);
    int lane = threadIdx.x & 63;
    const float* xr = in + (size_t)row * DM;
    float v[8];
    float s = 0.f;
#pragma unroll
    for (int i = 0; i < 8; i++) { v[i] = xr[lane + i * 64]; s += v[i]; }
#pragma unroll
    for (int o = 32; o >= 1; o >>= 1) s += __shfl_xor(s, o);
    float mu = s * (1.f / 512.f);
    float var = 0.f;
#pragma unroll
    for (int i = 0; i < 8; i++) { float d = v[i] - mu; var = fmaf(d, d, var); }
#pragma unroll
    for (int o = 32; o >= 1; o >>= 1) var += __shfl_xor(var, o);
    var *= (1.f / 512.f);
    float rstd = rsqrtf(var + 1e-5f);
    int t = row & (LSEQ - 1);
#pragma unroll
    for (int i = 0; i < 8; i++) {
        int c = lane + i * 64;
        float o = (v[i] - mu) * rstd * g[c] + bb[c];
        if (ADDPOS) o += pos[t * DM + c];
        out[(size_t)row * DM + c] = o;
    }
}

// ---------------- generic fp32 GEMM: C[M=4096][N] = epi(A[M][K(lda)] * W[N][K]^T) ----------------
// EPI: 0 = none, 1 = +bias then softplus
template<int EPI>
__global__ __launch_bounds__(256) void gemm_kernel(
    const float* __restrict__ A, int lda,
    const float* __restrict__ Wm,
    const float* __restrict__ bias,
    float* __restrict__ C, int N, int K)
{
    const int m0 = blockIdx.x * 64;
    const int n0 = blockIdx.y * 64;
    const int tid = threadIdx.x;
    const int tx = tid & 15, ty = tid >> 4;

    __shared__ float As[16][64];
    __shared__ float Ws[16][64];

    float acc[4][4];
#pragma unroll
    for (int i = 0; i < 4; i++)
#pragma unroll
        for (int j = 0; j < 4; j++) acc[i][j] = 0.f;

    const int am = tid >> 2;          // 0..63
    const int ak = (tid & 3) * 4;     // 0,4,8,12

    for (int k0 = 0; k0 < K; k0 += 16) {
        float4 av = *(const float4*)&A[(size_t)(m0 + am) * lda + k0 + ak];
        float4 wv = *(const float4*)&Wm[(size_t)(n0 + am) * K + k0 + ak];
        __syncthreads();
        As[ak + 0][am] = av.x; As[ak + 1][am] = av.y; As[ak + 2][am] = av.z; As[ak + 3][am] = av.w;
        Ws[ak + 0][am] = wv.x; Ws[ak + 1][am] = wv.y; Ws[ak + 2][am] = wv.z; Ws[ak + 3][am] = wv.w;
        __syncthreads();
#pragma unroll
        for (int kk = 0; kk < 16; kk++) {
            float4 a = *(const float4*)&As[kk][ty * 4];
            float4 w = *(const float4*)&Ws[kk][tx * 4];
            acc[0][0] = fmaf(a.x, w.x, acc[0][0]); acc[0][1] = fmaf(a.x, w.y, acc[0][1]);
            acc[0][2] = fmaf(a.x, w.z, acc[0][2]); acc[0][3] = fmaf(a.x, w.w, acc[0][3]);
            acc[1][0] = fmaf(a.y, w.x, acc[1][0]); acc[1][1] = fmaf(a.y, w.y, acc[1][1]);
            acc[1][2] = fmaf(a.y, w.z, acc[1][2]); acc[1][3] = fmaf(a.y, w.w, acc[1][3]);
            acc[2][0] = fmaf(a.z, w.x, acc[2][0]); acc[2][1] = fmaf(a.z, w.y, acc[2][1]);
            acc[2][2] = fmaf(a.z, w.z, acc[2][2]); acc[2][3] = fmaf(a.z, w.w, acc[2][3]);
            acc[3][0] = fmaf(a.w, w.x, acc[3][0]); acc[3][1] = fmaf(a.w, w.y, acc[3][1]);
            acc[3][2] = fmaf(a.w, w.z, acc[3][2]); acc[3][3] = fmaf(a.w, w.w, acc[3][3]);
        }
    }

#pragma unroll
    for (int i = 0; i < 4; i++) {
        float4 o;
        float r[4];
#pragma unroll
        for (int j = 0; j < 4; j++) {
            float v = acc[i][j];
            if (EPI == 1) {
                v += bias[n0 + tx * 4 + j];
                v = fmaxf(v, 0.f) + log1pf(expf(-fabsf(v)));   // softplus, stable
            }
            r[j] = v;
        }
        o.x = r[0]; o.y = r[1]; o.z = r[2]; o.w = r[3];
        *(float4*)&C[(size_t)(m0 + ty * 4 + i) * N + n0 + tx * 4] = o;
    }
}

// ---------------- depthwise causal conv(4) + silu ----------------
__global__ void dwconv_silu_kernel(const float* __restrict__ xz, const float* __restrict__ cw,
                                   const float* __restrict__ cb, float* __restrict__ xc) {
    int idx = blockIdx.x * 256 + threadIdx.x;   // over MROWS*DI
    int d = idx & (DI - 1);
    int r = idx >> 10;                          // row = b*L + t
    int tl = r & (LSEQ - 1);
    float acc = cb[d];
#pragma unroll
    for (int k = 0; k < DCONVN; k++) {
        int ts = tl - 3 + k;
        if (ts >= 0) acc = fmaf(xz[(size_t)(r - 3 + k) * (2 * DI) + d], cw[d * DCONVN + k], acc);
    }
    float sig = 1.f / (1.f + expf(-acc));
    xc[idx] = acc * sig;
}

// ---------------- selective scan ----------------
// thread = (d_local, s); block = 16 d x 16 s; grid = B * (DI/16)
__global__ __launch_bounds__(256) void scan_kernel(
    const float* __restrict__ dt, const float* __restrict__ xc,
    const float* __restrict__ dbc, const float* __restrict__ xz,
    const float* __restrict__ A_log, const float* __restrict__ Dp,
    float* __restrict__ y)
{
    int s  = threadIdx.x & 15;
    int dl = threadIdx.x >> 4;
    int d0 = (blockIdx.x & 63) * 16;
    int b  = blockIdx.x >> 6;
    int d  = d0 + dl;

    float Aval = -expf(A_log[d * DSTATE + s]);
    float Dval = Dp[d];
    float h = 0.f;
    int rowbase = b * LSEQ;

    for (int t = 0; t < LSEQ; t++) {
        int r = rowbase + t;
        float dtv = dt[(size_t)r * DI + d];
        float xcv = xc[(size_t)r * DI + d];
        float Bv  = dbc[(size_t)r * 64 + DTRANK + s];
        float Cv  = dbc[(size_t)r * 64 + DTRANK + DSTATE + s];
        float e = expf(dtv * Aval);
        h = fmaf(e, h, dtv * xcv * Bv);
        float p = h * Cv;
        p += __shfl_xor(p, 1); p += __shfl_xor(p, 2);
        p += __shfl_xor(p, 4); p += __shfl_xor(p, 8);
        if (s == 0) {
            float zv = xz[(size_t)r * (2 * DI) + DI + d];
            float zsig = 1.f / (1.f + expf(-zv));
            y[(size_t)r * DI + d] = (p + Dval * xcv) * (zv * zsig);
        }
    }
}

// ---------------- final FC: (B,512) @ fc_w(256,512)^T + fc_b ----------------
__global__ void fc_kernel(const float* __restrict__ x, const float* __restrict__ fcw,
                          const float* __restrict__ fcb, float* __restrict__ out) {
    int b = blockIdx.x;
    int v = threadIdx.x;   // 0..255
    __shared__ float rep[DM];
    const float* xr = x + (size_t)(b * LSEQ + LSEQ - 1) * DM;
    for (int i = threadIdx.x; i < DM; i += 256) rep[i] = xr[i];
    __syncthreads();
    float acc = fcb[v];
    for (int k = 0; k < DM; k++) acc = fmaf(rep[k], fcw[v * DM + k], acc);
    out[b * VOCABN + v] = acc;
}

extern "C" void kernel_launch(void* const* d_in, const int* in_sizes, int n_in,
                              void* d_out, int out_size, void* d_ws, size_t ws_size,
                              hipStream_t stream) {
    const int*   tokens    = (const int*)  d_in[0];
    const float* emb       = (const float*)d_in[1];
    const float* conv1_w   = (const float*)d_in[2];
    const float* conv1_b   = (const float*)d_in[3];
    const float* ln1_g     = (const float*)d_in[4];
    const float* ln1_b     = (const float*)d_in[5];
    const float* conv2_w   = (const float*)d_in[6];
    const float* conv2_b   = (const float*)d_in[7];
    const float* ln2_g     = (const float*)d_in[8];
    const float* ln2_b     = (const float*)d_in[9];
    const float* pos_emb   = (const float*)d_in[10];
    const float* in_proj_w = (const float*)d_in[11];
    const float* conv_w    = (const float*)d_in[12];
    const float* conv_b    = (const float*)d_in[13];
    const float* x_proj_w  = (const float*)d_in[14];
    const float* dt_proj_w = (const float*)d_in[15];
    const float* dt_proj_b = (const float*)d_in[16];
    const float* A_log     = (const float*)d_in[17];
    const float* Dp_all    = (const float*)d_in[18];
    const float* out_proj_w= (const float*)d_in[19];
    const float* fc_w      = (const float*)d_in[20];
    const float* fc_b      = (const float*)d_in[21];

    float* ws = (float*)d_ws;
    float* X   = ws;                         // (B,L,512)   2,097,152
    float* T1  = X  + 2097152;               // (B,L,512)   2,097,152
    float* XZ  = T1 + 2097152;               // (B,L,2048)  8,388,608
    float* XC  = XZ + 8388608;               // (B,L,1024)  4,194,304
    float* DT  = XC + 4194304;               // (B,L,1024)  4,194,304
    float* Y   = DT + 4194304;               // (B,L,1024)  4,194,304
    float* DBC = Y  + 4194304;               // (B,L,64)      262,144
    // aliases (lifetimes disjoint):
    float* X0  = XZ;                         // (B,L,384) inside XZ (pre-mamba only)
    float* WT1 = XC;                         // 983,040 inside XC (pre-mamba only)
    float* WT2 = XC + 983040;                // 786,432

    // frontend
    transpose_w_kernel<EMBN, 5><<<(512 * EMBN * 5 + 255) / 256, 256, 0, stream>>>(conv1_w, WT1);
    transpose_w_kernel<DM,   3><<<(512 * DM   * 3 + 255) / 256, 256, 0, stream>>>(conv2_w, WT2);
    embed_kernel<<<(MROWS * EMBN) / 256, 256, 0, stream>>>(tokens, emb, X0);
    conv_gelu_kernel<EMBN, 5, 2, 128><<<dim3(MROWS / 64, 8), 256, 0, stream>>>(X0, WT1, conv1_b, T1);
    ln_kernel<false><<<MROWS / 4, 256, 0, stream>>>(T1, ln1_g, ln1_b, nullptr, X);
    conv_gelu_kernel<DM, 3, 1, 128><<<dim3(MROWS / 64, 8), 256, 0, stream>>>(X, WT2, conv2_b, T1);
    ln_kernel<true><<<MROWS / 4, 256, 0, stream>>>(T1, ln2_g, ln2_b, pos_emb, X);

    // mamba layers
    for (int l = 0; l < NLAYER; l++) {
        gemm_kernel<0><<<dim3(MROWS / 64, (2 * DI) / 64), 256, 0, stream>>>(
            X, DM, in_proj_w + (size_t)l * 2 * DI * DM, nullptr, XZ, 2 * DI, DM);
        dwconv_silu_kernel<<<(MROWS * DI) / 256, 256, 0, stream>>>(
            XZ, conv_w + (size_t)l * DI * DCONVN, conv_b + (size_t)l * DI, XC);
        gemm_kernel<0><<<dim3(MROWS / 64, 1), 256, 0, stream>>>(
            XC, DI, x_proj_w + (size_t)l * 64 * DI, nullptr, DBC, 64, DI);
        gemm_kernel<1><<<dim3(MROWS / 64, DI / 64), 256, 0, stream>>>(
            DBC, 64, dt_proj_w + (size_t)l * DI * DTRANK, dt_proj_b + (size_t)l * DI, DT, DI, DTRANK);
        scan_kernel<<<BBATCH * (DI / 16), 256, 0, stream>>>(
            DT, XC, DBC, XZ, A_log + (size_t)l * DI * DSTATE, Dp_all + (size_t)l * DI, Y);
        gemm_kernel<0><<<dim3(MROWS / 64, DM / 64), 256, 0, stream>>>(
            Y, DI, out_proj_w + (size_t)l * DM * DI, nullptr, X, DM, DI);
    }

    fc_kernel<<<BBATCH, 256, 0, stream>>>(X, fc_w, fc_b, (float*)d_out);
}

// Round 2
// 4043.783 us; speedup vs baseline: 3.8198x; 3.8198x over previous
//
#include <hip/hip_runtime.h>
#include <hip/hip_bf16.h>
#include <math.h>

#define VOCABN 256
#define EMBN   384
#define DM     512
#define DI     1024
#define DSTATE 16
#define DCONVN 4
#define DTRANK 32
#define NLAYER 8
#define BBATCH 2
#define LSEQ   2048
#define MROWS  (BBATCH*LSEQ)   // 4096
#define SCHUNK 128
#define NCHUNK (LSEQ/SCHUNK)   // 16

// ---------------- weight transpose: w[co][ci][k] -> wt[k][ci][co] ----------------
template<int CI, int CK>
__global__ void transpose_w_kernel(const float* __restrict__ w, float* __restrict__ wt) {
    int idx = blockIdx.x * 256 + threadIdx.x;
    int total = 512 * CI * CK;
    if (idx >= total) return;
    int k  = idx % CK;
    int ci = (idx / CK) % CI;
    int co = idx / (CK * CI);
    wt[(k * CI + ci) * 512 + co] = w[idx];
}

// ---------------- embedding gather ----------------
__global__ void embed_kernel(const int* __restrict__ tok, const float* __restrict__ emb,
                             float* __restrict__ x0) {
    int idx = blockIdx.x * 256 + threadIdx.x;   // over MROWS*EMBN
    int c = idx % EMBN;
    int t = idx / EMBN;
    x0[idx] = emb[tok[t] * EMBN + c];
}

__device__ __forceinline__ float gelu_exact(float x) {
    return 0.5f * x * (1.f + erff(x * 0.70710678118654752f));
}

// ---------------- conv over time + bias + GELU ----------------
template<int CI, int CK, int PAD, int CICHUNK>
__global__ __launch_bounds__(256) void conv_gelu_kernel(
    const float* __restrict__ x, const float* __restrict__ wt,
    const float* __restrict__ bias, float* __restrict__ out)
{
    const int t0   = blockIdx.x * 64;          // global row base (b*L + t)
    const int co0  = blockIdx.y * 64;
    const int lane = threadIdx.x & 63;
    const int row  = threadIdx.x >> 6;         // 0..3
    const int co   = co0 + lane;
    const int b    = t0 / LSEQ;
    const int tb   = t0 - b * LSEQ;

    const int W = 64 + CK - 1;                 // staged window width
    __shared__ float xs[CICHUNK][69];          // pitch 69 kills write conflicts

    float acc[16];
#pragma unroll
    for (int i = 0; i < 16; i++) acc[i] = 0.f;

    for (int ci0 = 0; ci0 < CI; ci0 += CICHUNK) {
        for (int f = threadIdx.x; f < W * CICHUNK; f += 256) {
            int tl = f / CICHUNK;
            int cc = f % CICHUNK;
            int t  = tb - PAD + tl;
            float v = 0.f;
            if (t >= 0 && t < LSEQ) v = x[(b * LSEQ + t) * CI + ci0 + cc];
            xs[cc][tl] = v;
        }
        __syncthreads();

        for (int cc = 0; cc < CICHUNK; cc++) {
            float xv[16 + CK - 1];
#pragma unroll
            for (int j = 0; j < 16 + CK - 1; j++) xv[j] = xs[cc][row * 16 + j];
            float wv[CK];
#pragma unroll
            for (int k = 0; k < CK; k++) wv[k] = wt[(k * CI + ci0 + cc) * 512 + co];
#pragma unroll
            for (int k = 0; k < CK; k++)
#pragma unroll
                for (int i = 0; i < 16; i++) acc[i] = fmaf(xv[i + k], wv[k], acc[i]);
        }
        __syncthreads();
    }

    float bv = bias[co];
#pragma unroll
    for (int i = 0; i < 16; i++) {
        int r = t0 + row * 16 + i;
        out[r * 512 + co] = gelu_exact(acc[i] + bv);
    }
}

// ---------------- layernorm over 512, optional +pos_emb ----------------
template<bool ADDPOS>
__global__ __launch_bounds__(256) void ln_kernel(
    const float* __restrict__ in, const float* __restrict__ g, const float* __restrict__ bb,
    const float* __restrict__ pos, float* __restrict__ out)
{
    int row  = blockIdx.x * 4 + (threadIdx.x >> 6);
    int lane = threadIdx.x & 63;
    const float* xr = in + (size_t)row * DM;
    float v[8];
    float s = 0.f;
#pragma unroll
    for (int i = 0; i < 8; i++) { v[i] = xr[lane + i * 64]; s += v[i]; }
#pragma unroll
    for (int o = 32; o >= 1; o >>= 1) s += __shfl_xor(s, o);
    float mu = s * (1.f / 512.f);
    float var = 0.f;
#pragma unroll
    for (int i = 0; i < 8; i++) { float d = v[i] - mu; var = fmaf(d, d, var); }
#pragma unroll
    for (int o = 32; o >= 1; o >>= 1) var += __shfl_xor(var, o);
    var *= (1.f / 512.f);
    float rstd = rsqrtf(var + 1e-5f);
    int t = row & (LSEQ - 1);
#pragma unroll
    for (int i = 0; i < 8; i++) {
        int c = lane + i * 64;
        float o = (v[i] - mu) * rstd * g[c] + bb[c];
        if (ADDPOS) o += pos[t * DM + c];
        out[(size_t)row * DM + c] = o;
    }
}

// ---------------- generic fp32 GEMM: C[M=4096][N] = epi(A[M][K(lda)] * W[N][K]^T) ----------------
template<int EPI>
__global__ __launch_bounds__(256) void gemm_kernel(
    const float* __restrict__ A, int lda,
    const float* __restrict__ Wm,
    const float* __restrict__ bias,
    float* __restrict__ C, int N, int K)
{
    const int m0 = blockIdx.x * 64;
    const int n0 = blockIdx.y * 64;
    const int tid = threadIdx.x;
    const int tx = tid & 15, ty = tid >> 4;

    __shared__ float As[16][64];
    __shared__ float Ws[16][64];

    float acc[4][4];
#pragma unroll
    for (int i = 0; i < 4; i++)
#pragma unroll
        for (int j = 0; j < 4; j++) acc[i][j] = 0.f;

    const int am = tid >> 2;          // 0..63
    const int ak = (tid & 3) * 4;     // 0,4,8,12

    for (int k0 = 0; k0 < K; k0 += 16) {
        float4 av = *(const float4*)&A[(size_t)(m0 + am) * lda + k0 + ak];
        float4 wv = *(const float4*)&Wm[(size_t)(n0 + am) * K + k0 + ak];
        __syncthreads();
        As[ak + 0][am] = av.x; As[ak + 1][am] = av.y; As[ak + 2][am] = av.z; As[ak + 3][am] = av.w;
        Ws[ak + 0][am] = wv.x; Ws[ak + 1][am] = wv.y; Ws[ak + 2][am] = wv.z; Ws[ak + 3][am] = wv.w;
        __syncthreads();
#pragma unroll
        for (int kk = 0; kk < 16; kk++) {
            float4 a = *(const float4*)&As[kk][ty * 4];
            float4 w = *(const float4*)&Ws[kk][tx * 4];
            acc[0][0] = fmaf(a.x, w.x, acc[0][0]); acc[0][1] = fmaf(a.x, w.y, acc[0][1]);
            acc[0][2] = fmaf(a.x, w.z, acc[0][2]); acc[0][3] = fmaf(a.x, w.w, acc[0][3]);
            acc[1][0] = fmaf(a.y, w.x, acc[1][0]); acc[1][1] = fmaf(a.y, w.y, acc[1][1]);
            acc[1][2] = fmaf(a.y, w.z, acc[1][2]); acc[1][3] = fmaf(a.y, w.w, acc[1][3]);
            acc[2][0] = fmaf(a.z, w.x, acc[2][0]); acc[2][1] = fmaf(a.z, w.y, acc[2][1]);
            acc[2][2] = fmaf(a.z, w.z, acc[2][2]); acc[2][3] = fmaf(a.z, w.w, acc[2][3]);
            acc[3][0] = fmaf(a.w, w.x, acc[3][0]); acc[3][1] = fmaf(a.w, w.y, acc[3][1]);
            acc[3][2] = fmaf(a.w, w.z, acc[3][2]); acc[3][3] = fmaf(a.w, w.w, acc[3][3]);
        }
    }

#pragma unroll
    for (int i = 0; i < 4; i++) {
        float4 o;
        float r[4];
#pragma unroll
        for (int j = 0; j < 4; j++) {
            float v = acc[i][j];
            if (EPI == 1) {
                v += bias[n0 + tx * 4 + j];
                v = fmaxf(v, 0.f) + log1pf(expf(-fabsf(v)));   // softplus, stable
            }
            r[j] = v;
        }
        o.x = r[0]; o.y = r[1]; o.z = r[2]; o.w = r[3];
        *(float4*)&C[(size_t)(m0 + ty * 4 + i) * N + n0 + tx * 4] = o;
    }
}

// ---------------- depthwise causal conv(4) + silu ----------------
__global__ void dwconv_silu_kernel(const float* __restrict__ xz, const float* __restrict__ cw,
                                   const float* __restrict__ cb, float* __restrict__ xc) {
    int idx = blockIdx.x * 256 + threadIdx.x;   // over MROWS*DI
    int d = idx & (DI - 1);
    int r = idx >> 10;                          // row = b*L + t
    int tl = r & (LSEQ - 1);
    float acc = cb[d];
#pragma unroll
    for (int k = 0; k < DCONVN; k++) {
        int ts = tl - 3 + k;
        if (ts >= 0) acc = fmaf(xz[(size_t)(r - 3 + k) * (2 * DI) + d], cw[d * DCONVN + k], acc);
    }
    float sig = 1.f / (1.f + expf(-acc));
    xc[idx] = acc * sig;
}

// ---------------- chunked selective scan ----------------
// Pass 1: per (b, chunk, d, s) local scan with h0=0; store final state S and sum(dt).
// layout: block 256 = 16 d x 16 s; grid = B*NCHUNK*(DI/16)
__global__ __launch_bounds__(256) void scan_local_kernel(
    const float* __restrict__ dt, const float* __restrict__ xc,
    const float* __restrict__ dbc, const float* __restrict__ A_log,
    float* __restrict__ S, float* __restrict__ P)
{
    int s    = threadIdx.x & 15;
    int dl   = threadIdx.x >> 4;
    int dblk = blockIdx.x & 63;
    int c    = (blockIdx.x >> 6) & (NCHUNK - 1);
    int b    = blockIdx.x >> 10;           // /(64*NCHUNK)
    int d    = dblk * 16 + dl;

    float Aval = -expf(A_log[d * DSTATE + s]);
    float h = 0.f, sumdt = 0.f;
    int rowbase = b * LSEQ + c * SCHUNK;

#pragma unroll 4
    for (int t = 0; t < SCHUNK; t++) {
        int r = rowbase + t;
        float dtv = dt[(size_t)r * DI + d];
        float xcv = xc[(size_t)r * DI + d];
        float Bv  = dbc[(size_t)r * 64 + DTRANK + s];
        float e = expf(dtv * Aval);
        h = fmaf(e, h, dtv * xcv * Bv);
        sumdt += dtv;
    }
    size_t idx = ((size_t)(b * NCHUNK + c) * DI + d) * DSTATE + s;
    S[idx] = h;
    P[idx] = expf(Aval * sumdt);    // product of per-step exp factors
}

// Pass 2: per (b,d,s): H_0 = 0; H_{c+1} = P_c*H_c + S_c. Store chunk-initial states.
__global__ __launch_bounds__(256) void scan_combine_kernel(
    const float* __restrict__ S, const float* __restrict__ P, float* __restrict__ H)
{
    int idx = blockIdx.x * 256 + threadIdx.x;    // over B*DI*DSTATE = 32768
    int b = idx >> 14;
    int rem = idx & 16383;                        // d*16+s
    float h = 0.f;
#pragma unroll
    for (int c = 0; c < NCHUNK; c++) {
        size_t off = ((size_t)(b * NCHUNK + c) * DI) * DSTATE + rem;
        H[off] = h;
        h = fmaf(P[off], h, S[off]);
    }
}

// Pass 3: re-scan each chunk seeded with H; emit y = (h.C + D*xc) * z*silu(z)
__global__ __launch_bounds__(256) void scan_out_kernel(
    const float* __restrict__ dt, const float* __restrict__ xc,
    const float* __restrict__ dbc, const float* __restrict__ xz,
    const float* __restrict__ A_log, const float* __restrict__ Dp,
    const float* __restrict__ H, float* __restrict__ y)
{
    int s    = threadIdx.x & 15;
    int dl   = threadIdx.x >> 4;
    int dblk = blockIdx.x & 63;
    int c    = (blockIdx.x >> 6) & (NCHUNK - 1);
    int b    = blockIdx.x >> 10;
    int d    = dblk * 16 + dl;

    float Aval = -expf(A_log[d * DSTATE + s]);
    float Dval = Dp[d];
    float h = H[((size_t)(b * NCHUNK + c) * DI + d) * DSTATE + s];
    int rowbase = b * LSEQ + c * SCHUNK;

    for (int t = 0; t < SCHUNK; t++) {
        int r = rowbase + t;
        float dtv = dt[(size_t)r * DI + d];
        float xcv = xc[(size_t)r * DI + d];
        float Bv  = dbc[(size_t)r * 64 + DTRANK + s];
        float Cv  = dbc[(size_t)r * 64 + DTRANK + DSTATE + s];
        float e = expf(dtv * Aval);
        h = fmaf(e, h, dtv * xcv * Bv);
        float p = h * Cv;
        p += __shfl_xor(p, 1); p += __shfl_xor(p, 2);
        p += __shfl_xor(p, 4); p += __shfl_xor(p, 8);
        if (s == 0) {
            float zv = xz[(size_t)r * (2 * DI) + DI + d];
            float zsig = 1.f / (1.f + expf(-zv));
            y[(size_t)r * DI + d] = (p + Dval * xcv) * (zv * zsig);
        }
    }
}

// ---------------- final FC: (B,512) @ fc_w(256,512)^T + fc_b ----------------
__global__ void fc_kernel(const float* __restrict__ x, const float* __restrict__ fcw,
                          const float* __restrict__ fcb, float* __restrict__ out) {
    int b = blockIdx.x;
    int v = threadIdx.x;   // 0..255
    __shared__ float rep[DM];
    const float* xr = x + (size_t)(b * LSEQ + LSEQ - 1) * DM;
    for (int i = threadIdx.x; i < DM; i += 256) rep[i] = xr[i];
    __syncthreads();
    float acc = fcb[v];
    for (int k = 0; k < DM; k++) acc = fmaf(rep[k], fcw[v * DM + k], acc);
    out[b * VOCABN + v] = acc;
}

extern "C" void kernel_launch(void* const* d_in, const int* in_sizes, int n_in,
                              void* d_out, int out_size, void* d_ws, size_t ws_size,
                              hipStream_t stream) {
    const int*   tokens    = (const int*)  d_in[0];
    const float* emb       = (const float*)d_in[1];
    const float* conv1_w   = (const float*)d_in[2];
    const float* conv1_b   = (const float*)d_in[3];
    const float* ln1_g     = (const float*)d_in[4];
    const float* ln1_b     = (const float*)d_in[5];
    const float* conv2_w   = (const float*)d_in[6];
    const float* conv2_b   = (const float*)d_in[7];
    const float* ln2_g     = (const float*)d_in[8];
    const float* ln2_b     = (const float*)d_in[9];
    const float* pos_emb   = (const float*)d_in[10];
    const float* in_proj_w = (const float*)d_in[11];
    const float* conv_w    = (const float*)d_in[12];
    const float* conv_b    = (const float*)d_in[13];
    const float* x_proj_w  = (const float*)d_in[14];
    const float* dt_proj_w = (const float*)d_in[15];
    const float* dt_proj_b = (const float*)d_in[16];
    const float* A_log     = (const float*)d_in[17];
    const float* Dp_all    = (const float*)d_in[18];
    const float* out_proj_w= (const float*)d_in[19];
    const float* fc_w      = (const float*)d_in[20];
    const float* fc_b      = (const float*)d_in[21];

    float* ws = (float*)d_ws;
    float* X   = ws;                         // (B,L,512)   2,097,152
    float* T1  = X  + 2097152;               // (B,L,512)   2,097,152 (frontend only)
    float* XZ  = T1 + 2097152;               // (B,L,2048)  8,388,608
    float* XC  = XZ + 8388608;               // (B,L,1024)  4,194,304
    float* DT  = XC + 4194304;               // (B,L,1024)  4,194,304
    float* Y   = DT + 4194304;               // (B,L,1024)  4,194,304
    float* DBC = Y  + 4194304;               // (B,L,64)      262,144
    // aliases (lifetimes disjoint):
    float* X0  = XZ;                         // (B,L,384) inside XZ (pre-mamba only)
    float* WT1 = XC;                         // 983,040 inside XC (pre-mamba only)
    float* WT2 = XC + 983040;                // 786,432
    // scan chunk state aliases inside T1 (dead after frontend): 3 x 524,288
    float* SCN_S = T1;
    float* SCN_P = T1 + 524288;
    float* SCN_H = T1 + 1048576;

    // frontend
    transpose_w_kernel<EMBN, 5><<<(512 * EMBN * 5 + 255) / 256, 256, 0, stream>>>(conv1_w, WT1);
    transpose_w_kernel<DM,   3><<<(512 * DM   * 3 + 255) / 256, 256, 0, stream>>>(conv2_w, WT2);
    embed_kernel<<<(MROWS * EMBN) / 256, 256, 0, stream>>>(tokens, emb, X0);
    conv_gelu_kernel<EMBN, 5, 2, 128><<<dim3(MROWS / 64, 8), 256, 0, stream>>>(X0, WT1, conv1_b, T1);
    ln_kernel<false><<<MROWS / 4, 256, 0, stream>>>(T1, ln1_g, ln1_b, nullptr, X);
    conv_gelu_kernel<DM, 3, 1, 128><<<dim3(MROWS / 64, 8), 256, 0, stream>>>(X, WT2, conv2_b, T1);
    ln_kernel<true><<<MROWS / 4, 256, 0, stream>>>(T1, ln2_g, ln2_b, pos_emb, X);

    // mamba layers
    for (int l = 0; l < NLAYER; l++) {
        gemm_kernel<0><<<dim3(MROWS / 64, (2 * DI) / 64), 256, 0, stream>>>(
            X, DM, in_proj_w + (size_t)l * 2 * DI * DM, nullptr, XZ, 2 * DI, DM);
        dwconv_silu_kernel<<<(MROWS * DI) / 256, 256, 0, stream>>>(
            XZ, conv_w + (size_t)l * DI * DCONVN, conv_b + (size_t)l * DI, XC);
        gemm_kernel<0><<<dim3(MROWS / 64, 1), 256, 0, stream>>>(
            XC, DI, x_proj_w + (size_t)l * 64 * DI, nullptr, DBC, 64, DI);
        gemm_kernel<1><<<dim3(MROWS / 64, DI / 64), 256, 0, stream>>>(
            DBC, 64, dt_proj_w + (size_t)l * DI * DTRANK, dt_proj_b + (size_t)l * DI, DT, DI, DTRANK);
        scan_local_kernel<<<BBATCH * NCHUNK * (DI / 16), 256, 0, stream>>>(
            DT, XC, DBC, A_log + (size_t)l * DI * DSTATE, SCN_S, SCN_P);
        scan_combine_kernel<<<(BBATCH * DI * DSTATE) / 256, 256, 0, stream>>>(
            SCN_S, SCN_P, SCN_H);
        scan_out_kernel<<<BBATCH * NCHUNK * (DI / 16), 256, 0, stream>>>(
            DT, XC, DBC, XZ, A_log + (size_t)l * DI * DSTATE, Dp_all + (size_t)l * DI,
            SCN_H, Y);
        gemm_kernel<0><<<dim3(MROWS / 64, DM / 64), 256, 0, stream>>>(
            Y, DI, out_proj_w + (size_t)l * DM * DI, nullptr, X, DM, DI);
    }

    fc_kernel<<<BBATCH, 256, 0, stream>>>(X, fc_w, fc_b, (float*)d_out);
}

// Round 3
// 3103.633 us; speedup vs baseline: 4.9770x; 1.3029x over previous
//
#include <hip/hip_runtime.h>
#include <hip/hip_bf16.h>
#include <math.h>

#define VOCABN 256
#define EMBN   384
#define DM     512
#define DI     1024
#define DSTATE 16
#define DCONVN 4
#define DTRANK 32
#define NLAYER 8
#define BBATCH 2
#define LSEQ   2048
#define MROWS  (BBATCH*LSEQ)   // 4096
#define SCHUNK 128
#define NCHUNK (LSEQ/SCHUNK)   // 16

typedef short s8v  __attribute__((ext_vector_type(8)));
typedef float f32x4 __attribute__((ext_vector_type(4)));

// ---------------- weight transpose: w[co][ci][k] -> wt[k][ci][co] ----------------
template<int CI, int CK>
__global__ void transpose_w_kernel(const float* __restrict__ w, float* __restrict__ wt) {
    int idx = blockIdx.x * 256 + threadIdx.x;
    int total = 512 * CI * CK;
    if (idx >= total) return;
    int k  = idx % CK;
    int ci = (idx / CK) % CI;
    int co = idx / (CK * CI);
    wt[(k * CI + ci) * 512 + co] = w[idx];
}

// ---------------- embedding gather ----------------
__global__ void embed_kernel(const int* __restrict__ tok, const float* __restrict__ emb,
                             float* __restrict__ x0) {
    int idx = blockIdx.x * 256 + threadIdx.x;   // over MROWS*EMBN
    int c = idx % EMBN;
    int t = idx / EMBN;
    x0[idx] = emb[tok[t] * EMBN + c];
}

__device__ __forceinline__ float gelu_exact(float x) {
    return 0.5f * x * (1.f + erff(x * 0.70710678118654752f));
}

// ---------------- conv over time + bias + GELU ----------------
template<int CI, int CK, int PAD, int CICHUNK>
__global__ __launch_bounds__(256) void conv_gelu_kernel(
    const float* __restrict__ x, const float* __restrict__ wt,
    const float* __restrict__ bias, float* __restrict__ out)
{
    const int t0   = blockIdx.x * 64;          // global row base (b*L + t)
    const int co0  = blockIdx.y * 64;
    const int lane = threadIdx.x & 63;
    const int row  = threadIdx.x >> 6;         // 0..3
    const int co   = co0 + lane;
    const int b    = t0 / LSEQ;
    const int tb   = t0 - b * LSEQ;

    const int W = 64 + CK - 1;                 // staged window width
    __shared__ float xs[CICHUNK][69];          // pitch 69 kills write conflicts

    float acc[16];
#pragma unroll
    for (int i = 0; i < 16; i++) acc[i] = 0.f;

    for (int ci0 = 0; ci0 < CI; ci0 += CICHUNK) {
        for (int f = threadIdx.x; f < W * CICHUNK; f += 256) {
            int tl = f / CICHUNK;
            int cc = f % CICHUNK;
            int t  = tb - PAD + tl;
            float v = 0.f;
            if (t >= 0 && t < LSEQ) v = x[(b * LSEQ + t) * CI + ci0 + cc];
            xs[cc][tl] = v;
        }
        __syncthreads();

        for (int cc = 0; cc < CICHUNK; cc++) {
            float xv[16 + CK - 1];
#pragma unroll
            for (int j = 0; j < 16 + CK - 1; j++) xv[j] = xs[cc][row * 16 + j];
            float wv[CK];
#pragma unroll
            for (int k = 0; k < CK; k++) wv[k] = wt[(k * CI + ci0 + cc) * 512 + co];
#pragma unroll
            for (int k = 0; k < CK; k++)
#pragma unroll
                for (int i = 0; i < 16; i++) acc[i] = fmaf(xv[i + k], wv[k], acc[i]);
        }
        __syncthreads();
    }

    float bv = bias[co];
#pragma unroll
    for (int i = 0; i < 16; i++) {
        int r = t0 + row * 16 + i;
        out[r * 512 + co] = gelu_exact(acc[i] + bv);
    }
}

// ---------------- layernorm over 512, optional +pos_emb ----------------
template<bool ADDPOS>
__global__ __launch_bounds__(256) void ln_kernel(
    const float* __restrict__ in, const float* __restrict__ g, const float* __restrict__ bb,
    const float* __restrict__ pos, float* __restrict__ out)
{
    int row  = blockIdx.x * 4 + (threadIdx.x >> 6);
    int lane = threadIdx.x & 63;
    const float* xr = in + (size_t)row * DM;
    float v[8];
    float s = 0.f;
#pragma unroll
    for (int i = 0; i < 8; i++) { v[i] = xr[lane + i * 64]; s += v[i]; }
#pragma unroll
    for (int o = 32; o >= 1; o >>= 1) s += __shfl_xor(s, o);
    float mu = s * (1.f / 512.f);
    float var = 0.f;
#pragma unroll
    for (int i = 0; i < 8; i++) { float d = v[i] - mu; var = fmaf(d, d, var); }
#pragma unroll
    for (int o = 32; o >= 1; o >>= 1) var += __shfl_xor(var, o);
    var *= (1.f / 512.f);
    float rstd = rsqrtf(var + 1e-5f);
    int t = row & (LSEQ - 1);
#pragma unroll
    for (int i = 0; i < 8; i++) {
        int c = lane + i * 64;
        float o = (v[i] - mu) * rstd * g[c] + bb[c];
        if (ADDPOS) o += pos[t * DM + c];
        out[(size_t)row * DM + c] = o;
    }
}

// ---------------- fp32 GEMM (kept for dt_proj, K=32) ----------------
template<int EPI>
__global__ __launch_bounds__(256) void gemm_kernel(
    const float* __restrict__ A, int lda,
    const float* __restrict__ Wm,
    const float* __restrict__ bias,
    float* __restrict__ C, int N, int K)
{
    const int m0 = blockIdx.x * 64;
    const int n0 = blockIdx.y * 64;
    const int tid = threadIdx.x;
    const int tx = tid & 15, ty = tid >> 4;

    __shared__ float As[16][64];
    __shared__ float Ws[16][64];

    float acc[4][4];
#pragma unroll
    for (int i = 0; i < 4; i++)
#pragma unroll
        for (int j = 0; j < 4; j++) acc[i][j] = 0.f;

    const int am = tid >> 2;          // 0..63
    const int ak = (tid & 3) * 4;     // 0,4,8,12

    for (int k0 = 0; k0 < K; k0 += 16) {
        float4 av = *(const float4*)&A[(size_t)(m0 + am) * lda + k0 + ak];
        float4 wv = *(const float4*)&Wm[(size_t)(n0 + am) * K + k0 + ak];
        __syncthreads();
        As[ak + 0][am] = av.x; As[ak + 1][am] = av.y; As[ak + 2][am] = av.z; As[ak + 3][am] = av.w;
        Ws[ak + 0][am] = wv.x; Ws[ak + 1][am] = wv.y; Ws[ak + 2][am] = wv.z; Ws[ak + 3][am] = wv.w;
        __syncthreads();
#pragma unroll
        for (int kk = 0; kk < 16; kk++) {
            float4 a = *(const float4*)&As[kk][ty * 4];
            float4 w = *(const float4*)&Ws[kk][tx * 4];
            acc[0][0] = fmaf(a.x, w.x, acc[0][0]); acc[0][1] = fmaf(a.x, w.y, acc[0][1]);
            acc[0][2] = fmaf(a.x, w.z, acc[0][2]); acc[0][3] = fmaf(a.x, w.w, acc[0][3]);
            acc[1][0] = fmaf(a.y, w.x, acc[1][0]); acc[1][1] = fmaf(a.y, w.y, acc[1][1]);
            acc[1][2] = fmaf(a.y, w.z, acc[1][2]); acc[1][3] = fmaf(a.y, w.w, acc[1][3]);
            acc[2][0] = fmaf(a.z, w.x, acc[2][0]); acc[2][1] = fmaf(a.z, w.y, acc[2][1]);
            acc[2][2] = fmaf(a.z, w.z, acc[2][2]); acc[2][3] = fmaf(a.z, w.w, acc[2][3]);
            acc[3][0] = fmaf(a.w, w.x, acc[3][0]); acc[3][1] = fmaf(a.w, w.y, acc[3][1]);
            acc[3][2] = fmaf(a.w, w.z, acc[3][2]); acc[3][3] = fmaf(a.w, w.w, acc[3][3]);
        }
    }

#pragma unroll
    for (int i = 0; i < 4; i++) {
        float4 o;
        float r[4];
#pragma unroll
        for (int j = 0; j < 4; j++) {
            float v = acc[i][j];
            if (EPI == 1) {
                v += bias[n0 + tx * 4 + j];
                v = fmaxf(v, 0.f) + log1pf(expf(-fabsf(v)));   // softplus, stable
            }
            r[j] = v;
        }
        o.x = r[0]; o.y = r[1]; o.z = r[2]; o.w = r[3];
        *(float4*)&C[(size_t)(m0 + ty * 4 + i) * N + n0 + tx * 4] = o;
    }
}

// ---------------- split-bf16 helpers ----------------
__device__ __forceinline__ ushort f2bf(float f) {
    uint u = __float_as_uint(f);
    return (ushort)((u + 0x7fffu + ((u >> 16) & 1u)) >> 16);
}
__device__ __forceinline__ float bf2f(ushort h) {
    return __uint_as_float((uint)h << 16);
}
__device__ __forceinline__ void cvt4(float4 v, ushort4* hp, ushort4* lp) {
    ushort4 h, l;
    h.x = f2bf(v.x); h.y = f2bf(v.y); h.z = f2bf(v.z); h.w = f2bf(v.w);
    l.x = f2bf(v.x - bf2f(h.x));
    l.y = f2bf(v.y - bf2f(h.y));
    l.z = f2bf(v.z - bf2f(h.z));
    l.w = f2bf(v.w - bf2f(h.w));
    *hp = h; *lp = l;
}

// ---------------- MFMA split-bf16 GEMM: C[M][N] = A[M][K(lda)] * W[N][K]^T ----------------
// BM=128 fixed, 256 threads (4 waves). BN=128: waves 2x2 (64x64 each); BN=64: waves 4x1 (32x64).
// bf16x3: A*B ~= Ah*Bh + Ah*Bl + Al*Bh (fp32 accumulate in MFMA).
template<int BN>
__global__ __launch_bounds__(256) void gemm_mfma_kernel(
    const float* __restrict__ A, int lda,
    const float* __restrict__ Wm,
    float* __restrict__ C, int N, int K)
{
    constexpr int MR = (BN == 128) ? 4 : 2;
    constexpr int NR = 4;
    const int m0 = blockIdx.x * 128;
    const int n0 = blockIdx.y * BN;
    const int tid = threadIdx.x;
    const int wid = tid >> 6;
    const int lane = tid & 63;
    const int rb = (BN == 128) ? (wid >> 1) * 64 : wid * 32;
    const int cb = (BN == 128) ? (wid & 1) * 64 : 0;
    const int lr = lane & 15;         // row/col within 16x16 frag
    const int lk = (lane >> 4) * 8;   // k base within 32

    __shared__ alignas(16) ushort Ah[128][32];
    __shared__ alignas(16) ushort Al[128][32];
    __shared__ alignas(16) ushort Bh[BN][32];
    __shared__ alignas(16) ushort Bl[BN][32];

    f32x4 acc[MR][NR];
#pragma unroll
    for (int m = 0; m < MR; m++)
#pragma unroll
        for (int n = 0; n < NR; n++) acc[m][n] = (f32x4){0.f, 0.f, 0.f, 0.f};

    const int srow = tid >> 3;        // 0..31
    const int scol = (tid & 7) * 4;   // 0,4,...,28

    for (int k0 = 0; k0 < K; k0 += 32) {
        float4 av[4], wv[BN / 32];
#pragma unroll
        for (int i = 0; i < 4; i++)
            av[i] = *(const float4*)&A[(size_t)(m0 + srow + 32 * i) * lda + k0 + scol];
#pragma unroll
        for (int i = 0; i < BN / 32; i++)
            wv[i] = *(const float4*)&Wm[(size_t)(n0 + srow + 32 * i) * K + k0 + scol];

        __syncthreads();
#pragma unroll
        for (int i = 0; i < 4; i++)
            cvt4(av[i], (ushort4*)&Ah[srow + 32 * i][scol], (ushort4*)&Al[srow + 32 * i][scol]);
#pragma unroll
        for (int i = 0; i < BN / 32; i++)
            cvt4(wv[i], (ushort4*)&Bh[srow + 32 * i][scol], (ushort4*)&Bl[srow + 32 * i][scol]);
        __syncthreads();

        s8v ah[MR], al[MR], bh[NR], bl[NR];
#pragma unroll
        for (int m = 0; m < MR; m++) {
            ah[m] = *(const s8v*)&Ah[rb + m * 16 + lr][lk];
            al[m] = *(const s8v*)&Al[rb + m * 16 + lr][lk];
        }
#pragma unroll
        for (int n = 0; n < NR; n++) {
            bh[n] = *(const s8v*)&Bh[cb + n * 16 + lr][lk];
            bl[n] = *(const s8v*)&Bl[cb + n * 16 + lr][lk];
        }
#pragma unroll
        for (int m = 0; m < MR; m++)
#pragma unroll
            for (int n = 0; n < NR; n++) {
                acc[m][n] = __builtin_amdgcn_mfma_f32_16x16x32_bf16(ah[m], bh[n], acc[m][n], 0, 0, 0);
                acc[m][n] = __builtin_amdgcn_mfma_f32_16x16x32_bf16(ah[m], bl[n], acc[m][n], 0, 0, 0);
                acc[m][n] = __builtin_amdgcn_mfma_f32_16x16x32_bf16(al[m], bh[n], acc[m][n], 0, 0, 0);
            }
    }

    // C/D layout: col = lane&15, row = (lane>>4)*4 + reg   [m89-verified]
#pragma unroll
    for (int m = 0; m < MR; m++)
#pragma unroll
        for (int n = 0; n < NR; n++) {
#pragma unroll
            for (int r = 0; r < 4; r++) {
                int grow = m0 + rb + m * 16 + (lane >> 4) * 4 + r;
                int gcol = n0 + cb + n * 16 + lr;
                C[(size_t)grow * N + gcol] = acc[m][n][r];
            }
        }
}

// ---------------- depthwise causal conv(4) + silu ----------------
__global__ void dwconv_silu_kernel(const float* __restrict__ xz, const float* __restrict__ cw,
                                   const float* __restrict__ cb, float* __restrict__ xc) {
    int idx = blockIdx.x * 256 + threadIdx.x;   // over MROWS*DI
    int d = idx & (DI - 1);
    int r = idx >> 10;                          // row = b*L + t
    int tl = r & (LSEQ - 1);
    float acc = cb[d];
#pragma unroll
    for (int k = 0; k < DCONVN; k++) {
        int ts = tl - 3 + k;
        if (ts >= 0) acc = fmaf(xz[(size_t)(r - 3 + k) * (2 * DI) + d], cw[d * DCONVN + k], acc);
    }
    float sig = 1.f / (1.f + expf(-acc));
    xc[idx] = acc * sig;
}

// ---------------- chunked selective scan ----------------
__global__ __launch_bounds__(256) void scan_local_kernel(
    const float* __restrict__ dt, const float* __restrict__ xc,
    const float* __restrict__ dbc, const float* __restrict__ A_log,
    float* __restrict__ S, float* __restrict__ P)
{
    int s    = threadIdx.x & 15;
    int dl   = threadIdx.x >> 4;
    int dblk = blockIdx.x & 63;
    int c    = (blockIdx.x >> 6) & (NCHUNK - 1);
    int b    = blockIdx.x >> 10;           // /(64*NCHUNK)
    int d    = dblk * 16 + dl;

    float Aval = -expf(A_log[d * DSTATE + s]);
    float h = 0.f, sumdt = 0.f;
    int rowbase = b * LSEQ + c * SCHUNK;

#pragma unroll 4
    for (int t = 0; t < SCHUNK; t++) {
        int r = rowbase + t;
        float dtv = dt[(size_t)r * DI + d];
        float xcv = xc[(size_t)r * DI + d];
        float Bv  = dbc[(size_t)r * 64 + DTRANK + s];
        float e = expf(dtv * Aval);
        h = fmaf(e, h, dtv * xcv * Bv);
        sumdt += dtv;
    }
    size_t idx = ((size_t)(b * NCHUNK + c) * DI + d) * DSTATE + s;
    S[idx] = h;
    P[idx] = expf(Aval * sumdt);    // product of per-step exp factors
}

__global__ __launch_bounds__(256) void scan_combine_kernel(
    const float* __restrict__ S, const float* __restrict__ P, float* __restrict__ H)
{
    int idx = blockIdx.x * 256 + threadIdx.x;    // over B*DI*DSTATE = 32768
    int b = idx >> 14;
    int rem = idx & 16383;                        // d*16+s
    float h = 0.f;
#pragma unroll
    for (int c = 0; c < NCHUNK; c++) {
        size_t off = ((size_t)(b * NCHUNK + c) * DI) * DSTATE + rem;
        H[off] = h;
        h = fmaf(P[off], h, S[off]);
    }
}

__global__ __launch_bounds__(256) void scan_out_kernel(
    const float* __restrict__ dt, const float* __restrict__ xc,
    const float* __restrict__ dbc, const float* __restrict__ xz,
    const float* __restrict__ A_log, const float* __restrict__ Dp,
    const float* __restrict__ H, float* __restrict__ y)
{
    int s    = threadIdx.x & 15;
    int dl   = threadIdx.x >> 4;
    int dblk = blockIdx.x & 63;
    int c    = (blockIdx.x >> 6) & (NCHUNK - 1);
    int b    = blockIdx.x >> 10;
    int d    = dblk * 16 + dl;

    float Aval = -expf(A_log[d * DSTATE + s]);
    float Dval = Dp[d];
    float h = H[((size_t)(b * NCHUNK + c) * DI + d) * DSTATE + s];
    int rowbase = b * LSEQ + c * SCHUNK;

    for (int t = 0; t < SCHUNK; t++) {
        int r = rowbase + t;
        float dtv = dt[(size_t)r * DI + d];
        float xcv = xc[(size_t)r * DI + d];
        float Bv  = dbc[(size_t)r * 64 + DTRANK + s];
        float Cv  = dbc[(size_t)r * 64 + DTRANK + DSTATE + s];
        float e = expf(dtv * Aval);
        h = fmaf(e, h, dtv * xcv * Bv);
        float p = h * Cv;
        p += __shfl_xor(p, 1); p += __shfl_xor(p, 2);
        p += __shfl_xor(p, 4); p += __shfl_xor(p, 8);
        if (s == 0) {
            float zv = xz[(size_t)r * (2 * DI) + DI + d];
            float zsig = 1.f / (1.f + expf(-zv));
            y[(size_t)r * DI + d] = (p + Dval * xcv) * (zv * zsig);
        }
    }
}

// ---------------- final FC: (B,512) @ fc_w(256,512)^T + fc_b ----------------
__global__ void fc_kernel(const float* __restrict__ x, const float* __restrict__ fcw,
                          const float* __restrict__ fcb, float* __restrict__ out) {
    int b = blockIdx.x;
    int v = threadIdx.x;   // 0..255
    __shared__ float rep[DM];
    const float* xr = x + (size_t)(b * LSEQ + LSEQ - 1) * DM;
    for (int i = threadIdx.x; i < DM; i += 256) rep[i] = xr[i];
    __syncthreads();
    float acc = fcb[v];
    for (int k = 0; k < DM; k++) acc = fmaf(rep[k], fcw[v * DM + k], acc);
    out[b * VOCABN + v] = acc;
}

extern "C" void kernel_launch(void* const* d_in, const int* in_sizes, int n_in,
                              void* d_out, int out_size, void* d_ws, size_t ws_size,
                              hipStream_t stream) {
    const int*   tokens    = (const int*)  d_in[0];
    const float* emb       = (const float*)d_in[1];
    const float* conv1_w   = (const float*)d_in[2];
    const float* conv1_b   = (const float*)d_in[3];
    const float* ln1_g     = (const float*)d_in[4];
    const float* ln1_b     = (const float*)d_in[5];
    const float* conv2_w   = (const float*)d_in[6];
    const float* conv2_b   = (const float*)d_in[7];
    const float* ln2_g     = (const float*)d_in[8];
    const float* ln2_b     = (const float*)d_in[9];
    const float* pos_emb   = (const float*)d_in[10];
    const float* in_proj_w = (const float*)d_in[11];
    const float* conv_w    = (const float*)d_in[12];
    const float* conv_b    = (const float*)d_in[13];
    const float* x_proj_w  = (const float*)d_in[14];
    const float* dt_proj_w = (const float*)d_in[15];
    const float* dt_proj_b = (const float*)d_in[16];
    const float* A_log     = (const float*)d_in[17];
    const float* Dp_all    = (const float*)d_in[18];
    const float* out_proj_w= (const float*)d_in[19];
    const float* fc_w      = (const float*)d_in[20];
    const float* fc_b      = (const float*)d_in[21];

    float* ws = (float*)d_ws;
    float* X   = ws;                         // (B,L,512)   2,097,152
    float* T1  = X  + 2097152;               // (B,L,512)   2,097,152 (frontend only)
    float* XZ  = T1 + 2097152;               // (B,L,2048)  8,388,608
    float* XC  = XZ + 8388608;               // (B,L,1024)  4,194,304
    float* DT  = XC + 4194304;               // (B,L,1024)  4,194,304
    float* Y   = DT + 4194304;               // (B,L,1024)  4,194,304
    float* DBC = Y  + 4194304;               // (B,L,64)      262,144
    // aliases (lifetimes disjoint):
    float* X0  = XZ;                         // (B,L,384) inside XZ (pre-mamba only)
    float* WT1 = XC;                         // 983,040 inside XC (pre-mamba only)
    float* WT2 = XC + 983040;                // 786,432
    // scan chunk state aliases inside T1 (dead after frontend): 3 x 524,288
    float* SCN_S = T1;
    float* SCN_P = T1 + 524288;
    float* SCN_H = T1 + 1048576;

    // frontend
    transpose_w_kernel<EMBN, 5><<<(512 * EMBN * 5 + 255) / 256, 256, 0, stream>>>(conv1_w, WT1);
    transpose_w_kernel<DM,   3><<<(512 * DM   * 3 + 255) / 256, 256, 0, stream>>>(conv2_w, WT2);
    embed_kernel<<<(MROWS * EMBN) / 256, 256, 0, stream>>>(tokens, emb, X0);
    conv_gelu_kernel<EMBN, 5, 2, 128><<<dim3(MROWS / 64, 8), 256, 0, stream>>>(X0, WT1, conv1_b, T1);
    ln_kernel<false><<<MROWS / 4, 256, 0, stream>>>(T1, ln1_g, ln1_b, nullptr, X);
    conv_gelu_kernel<DM, 3, 1, 128><<<dim3(MROWS / 64, 8), 256, 0, stream>>>(X, WT2, conv2_b, T1);
    ln_kernel<true><<<MROWS / 4, 256, 0, stream>>>(T1, ln2_g, ln2_b, pos_emb, X);

    // mamba layers
    for (int l = 0; l < NLAYER; l++) {
        gemm_mfma_kernel<128><<<dim3(MROWS / 128, (2 * DI) / 128), 256, 0, stream>>>(
            X, DM, in_proj_w + (size_t)l * 2 * DI * DM, XZ, 2 * DI, DM);
        dwconv_silu_kernel<<<(MROWS * DI) / 256, 256, 0, stream>>>(
            XZ, conv_w + (size_t)l * DI * DCONVN, conv_b + (size_t)l * DI, XC);
        gemm_mfma_kernel<64><<<dim3(MROWS / 128, 1), 256, 0, stream>>>(
            XC, DI, x_proj_w + (size_t)l * 64 * DI, DBC, 64, DI);
        gemm_kernel<1><<<dim3(MROWS / 64, DI / 64), 256, 0, stream>>>(
            DBC, 64, dt_proj_w + (size_t)l * DI * DTRANK, dt_proj_b + (size_t)l * DI, DT, DI, DTRANK);
        scan_local_kernel<<<BBATCH * NCHUNK * (DI / 16), 256, 0, stream>>>(
            DT, XC, DBC, A_log + (size_t)l * DI * DSTATE, SCN_S, SCN_P);
        scan_combine_kernel<<<(BBATCH * DI * DSTATE) / 256, 256, 0, stream>>>(
            SCN_S, SCN_P, SCN_H);
        scan_out_kernel<<<BBATCH * NCHUNK * (DI / 16), 256, 0, stream>>>(
            DT, XC, DBC, XZ, A_log + (size_t)l * DI * DSTATE, Dp_all + (size_t)l * DI,
            SCN_H, Y);
        gemm_mfma_kernel<64><<<dim3(MROWS / 128, DM / 64), 256, 0, stream>>>(
            Y, DI, out_proj_w + (size_t)l * DM * DI, X, DM, DI);
    }

    fc_kernel<<<BBATCH, 256, 0, stream>>>(X, fc_w, fc_b, (float*)d_out);
}

// Round 4
// 2766.113 us; speedup vs baseline: 5.5842x; 1.1220x over previous
//
#include <hip/hip_runtime.h>
#include <hip/hip_bf16.h>
#include <math.h>

#define VOCABN 256
#define EMBN   384
#define DM     512
#define DI     1024
#define DSTATE 16
#define DCONVN 4
#define DTRANK 32
#define NLAYER 8
#define BBATCH 2
#define LSEQ   2048
#define MROWS  (BBATCH*LSEQ)   // 4096
#define SCHUNK 128
#define NCHUNK (LSEQ/SCHUNK)   // 16

typedef short s8v  __attribute__((ext_vector_type(8)));
typedef float f32x4 __attribute__((ext_vector_type(4)));

// ---------------- bf16 split/pack helpers ----------------
__device__ __forceinline__ ushort f2bf(float f) {
    uint u = __float_as_uint(f);
    return (ushort)((u + 0x7fffu + ((u >> 16) & 1u)) >> 16);
}
__device__ __forceinline__ float bf2f(ushort h) {
    return __uint_as_float((uint)h << 16);
}
// packed element: hi bf16 in high 16 bits, lo bf16 (residual) in low 16 bits
__device__ __forceinline__ uint packbf(float f) {
    ushort h = f2bf(f);
    ushort l = f2bf(f - bf2f(h));
    return ((uint)h << 16) | (uint)l;
}
__device__ __forceinline__ void unp4(uint4 p, ushort* hdst, ushort* ldst) {
    ushort4 h, l;
    h.x = (ushort)(p.x >> 16); l.x = (ushort)(p.x & 0xffffu);
    h.y = (ushort)(p.y >> 16); l.y = (ushort)(p.y & 0xffffu);
    h.z = (ushort)(p.z >> 16); l.z = (ushort)(p.z & 0xffffu);
    h.w = (ushort)(p.w >> 16); l.w = (ushort)(p.w & 0xffffu);
    *(ushort4*)hdst = h; *(ushort4*)ldst = l;
}

// ---------------- pack kernels ----------------
__global__ void pack3_kernel(const float* __restrict__ a, int na,
                             const float* __restrict__ b, int nb,
                             const float* __restrict__ c, int nc,
                             uint* __restrict__ pa, uint* __restrict__ pb, uint* __restrict__ pc) {
    int i = blockIdx.x * 256 + threadIdx.x;
    if (i < na) pa[i] = packbf(a[i]);
    else if (i < na + nb) pb[i - na] = packbf(b[i - na]);
    else if (i < na + nb + nc) pc[i - na - nb] = packbf(c[i - na - nb]);
}

// conv weights: w[co][ci][k] fp32 -> pw[k][co][ci] packed
template<int CI, int CK>
__global__ void pack_convw_kernel(const float* __restrict__ w, uint* __restrict__ pw) {
    int idx = blockIdx.x * 256 + threadIdx.x;
    if (idx >= 512 * CI * CK) return;
    int k  = idx % CK;
    int ci = (idx / CK) % CI;
    int co = idx / (CK * CI);
    pw[((size_t)(k * 512) + co) * CI + ci] = packbf(w[idx]);
}

// ---------------- embedding gather -> packed ----------------
__global__ void embed_kernel(const int* __restrict__ tok, const float* __restrict__ emb,
                             uint* __restrict__ px0) {
    int idx = blockIdx.x * 256 + threadIdx.x;   // over MROWS*EMBN
    int c = idx % EMBN;
    int t = idx / EMBN;
    px0[idx] = packbf(emb[tok[t] * EMBN + c]);
}

__device__ __forceinline__ float gelu_exact(float x) {
    return 0.5f * x * (1.f + erff(x * 0.70710678118654752f));
}

// ---------------- conv as implicit-GEMM MFMA (bf16x3) ----------------
// out[t][co] = gelu( bias[co] + sum_k sum_ci x[t-PAD+k][ci] * w[co][ci][k] )
// tile: 128 t-rows x 32 co. 4 waves, each 32 rows (MR=2) x 32 cols (NR=2).
template<int CI, int CK, int PAD>
__global__ __launch_bounds__(256) void conv_mfma_kernel(
    const uint* __restrict__ PA, const uint* __restrict__ PW,
    const float* __restrict__ bias, float* __restrict__ out)
{
    constexpr int ROWS = 128 + CK - 1;
    const int t0  = blockIdx.x * 128;
    const int co0 = blockIdx.y * 32;
    const int tid = threadIdx.x;
    const int wid = tid >> 6, lane = tid & 63;
    const int rb = wid * 32;
    const int lr = lane & 15, lk = (lane >> 4) * 8;
    const int bstart = (t0 / LSEQ) * LSEQ;

    __shared__ alignas(16) ushort Ah[ROWS][40], Al[ROWS][40];
    __shared__ alignas(16) ushort Bh[CK][32][40], Bl[CK][32][40];

    f32x4 acc[2][2];
#pragma unroll
    for (int m = 0; m < 2; m++)
#pragma unroll
        for (int n = 0; n < 2; n++) acc[m][n] = (f32x4){0.f, 0.f, 0.f, 0.f};

    for (int ci0 = 0; ci0 < CI; ci0 += 32) {
        __syncthreads();
        // stage A window (ROWS x 32 ci), zero outside batch segment
        for (int idx = tid; idx < ROWS * 8; idx += 256) {
            int r = idx >> 3, c4 = (idx & 7) * 4;
            int g = t0 - PAD + r;
            uint4 v = make_uint4(0u, 0u, 0u, 0u);
            if (g >= bstart && g < bstart + LSEQ)
                v = *(const uint4*)&PA[(size_t)g * CI + ci0 + c4];
            unp4(v, &Ah[r][c4], &Al[r][c4]);
        }
        // stage B: CK taps x 32 co x 32 ci
        for (int idx = tid; idx < CK * 32 * 8; idx += 256) {
            int k = idx >> 8;
            int r = (idx >> 3) & 31;
            int c4 = (idx & 7) * 4;
            uint4 v = *(const uint4*)&PW[((size_t)(k * 512) + co0 + r) * CI + ci0 + c4];
            unp4(v, &Bh[k][r][c4], &Bl[k][r][c4]);
        }
        __syncthreads();

#pragma unroll
        for (int k = 0; k < CK; k++) {
            s8v ah[2], al[2], bh[2], bl[2];
#pragma unroll
            for (int m = 0; m < 2; m++) {
                ah[m] = *(const s8v*)&Ah[rb + m * 16 + lr + k][lk];
                al[m] = *(const s8v*)&Al[rb + m * 16 + lr + k][lk];
            }
#pragma unroll
            for (int n = 0; n < 2; n++) {
                bh[n] = *(const s8v*)&Bh[k][n * 16 + lr][lk];
                bl[n] = *(const s8v*)&Bl[k][n * 16 + lr][lk];
            }
#pragma unroll
            for (int m = 0; m < 2; m++)
#pragma unroll
                for (int n = 0; n < 2; n++) {
                    acc[m][n] = __builtin_amdgcn_mfma_f32_16x16x32_bf16(ah[m], bh[n], acc[m][n], 0, 0, 0);
                    acc[m][n] = __builtin_amdgcn_mfma_f32_16x16x32_bf16(ah[m], bl[n], acc[m][n], 0, 0, 0);
                    acc[m][n] = __builtin_amdgcn_mfma_f32_16x16x32_bf16(al[m], bh[n], acc[m][n], 0, 0, 0);
                }
        }
    }

#pragma unroll
    for (int m = 0; m < 2; m++)
#pragma unroll
        for (int n = 0; n < 2; n++) {
            int gcol = co0 + n * 16 + lr;
            float bv = bias[gcol];
#pragma unroll
            for (int r = 0; r < 4; r++) {
                int grow = t0 + rb + m * 16 + (lane >> 4) * 4 + r;
                out[(size_t)grow * 512 + gcol] = gelu_exact(acc[m][n][r] + bv);
            }
        }
}

// ---------------- layernorm over 512, optional +pos_emb; packed or fp32 out ----------------
template<bool ADDPOS, bool PACK>
__global__ __launch_bounds__(256) void ln_kernel(
    const float* __restrict__ in, const float* __restrict__ g, const float* __restrict__ bb,
    const float* __restrict__ pos, float* __restrict__ out, uint* __restrict__ pout)
{
    int row  = blockIdx.x * 4 + (threadIdx.x >> 6);
    int lane = threadIdx.x & 63;
    const float* xr = in + (size_t)row * DM;
    float v[8];
    float s = 0.f;
#pragma unroll
    for (int i = 0; i < 8; i++) { v[i] = xr[lane + i * 64]; s += v[i]; }
#pragma unroll
    for (int o = 32; o >= 1; o >>= 1) s += __shfl_xor(s, o);
    float mu = s * (1.f / 512.f);
    float var = 0.f;
#pragma unroll
    for (int i = 0; i < 8; i++) { float d = v[i] - mu; var = fmaf(d, d, var); }
#pragma unroll
    for (int o = 32; o >= 1; o >>= 1) var += __shfl_xor(var, o);
    var *= (1.f / 512.f);
    float rstd = rsqrtf(var + 1e-5f);
    int t = row & (LSEQ - 1);
#pragma unroll
    for (int i = 0; i < 8; i++) {
        int c = lane + i * 64;
        float o = (v[i] - mu) * rstd * g[c] + bb[c];
        if (ADDPOS) o += pos[t * DM + c];
        if (PACK) pout[(size_t)row * DM + c] = packbf(o);
        else      out [(size_t)row * DM + c] = o;
    }
}

// ---------------- fp32 GEMM (kept for dt_proj, K=32) ----------------
template<int EPI>
__global__ __launch_bounds__(256) void gemm_kernel(
    const float* __restrict__ A, int lda,
    const float* __restrict__ Wm,
    const float* __restrict__ bias,
    float* __restrict__ C, int N, int K)
{
    const int m0 = blockIdx.x * 64;
    const int n0 = blockIdx.y * 64;
    const int tid = threadIdx.x;
    const int tx = tid & 15, ty = tid >> 4;

    __shared__ float As[16][64];
    __shared__ float Ws[16][64];

    float acc[4][4];
#pragma unroll
    for (int i = 0; i < 4; i++)
#pragma unroll
        for (int j = 0; j < 4; j++) acc[i][j] = 0.f;

    const int am = tid >> 2;          // 0..63
    const int ak = (tid & 3) * 4;     // 0,4,8,12

    for (int k0 = 0; k0 < K; k0 += 16) {
        float4 av = *(const float4*)&A[(size_t)(m0 + am) * lda + k0 + ak];
        float4 wv = *(const float4*)&Wm[(size_t)(n0 + am) * K + k0 + ak];
        __syncthreads();
        As[ak + 0][am] = av.x; As[ak + 1][am] = av.y; As[ak + 2][am] = av.z; As[ak + 3][am] = av.w;
        Ws[ak + 0][am] = wv.x; Ws[ak + 1][am] = wv.y; Ws[ak + 2][am] = wv.z; Ws[ak + 3][am] = wv.w;
        __syncthreads();
#pragma unroll
        for (int kk = 0; kk < 16; kk++) {
            float4 a = *(const float4*)&As[kk][ty * 4];
            float4 w = *(const float4*)&Ws[kk][tx * 4];
            acc[0][0] = fmaf(a.x, w.x, acc[0][0]); acc[0][1] = fmaf(a.x, w.y, acc[0][1]);
            acc[0][2] = fmaf(a.x, w.z, acc[0][2]); acc[0][3] = fmaf(a.x, w.w, acc[0][3]);
            acc[1][0] = fmaf(a.y, w.x, acc[1][0]); acc[1][1] = fmaf(a.y, w.y, acc[1][1]);
            acc[1][2] = fmaf(a.y, w.z, acc[1][2]); acc[1][3] = fmaf(a.y, w.w, acc[1][3]);
            acc[2][0] = fmaf(a.z, w.x, acc[2][0]); acc[2][1] = fmaf(a.z, w.y, acc[2][1]);
            acc[2][2] = fmaf(a.z, w.z, acc[2][2]); acc[2][3] = fmaf(a.z, w.w, acc[2][3]);
            acc[3][0] = fmaf(a.w, w.x, acc[3][0]); acc[3][1] = fmaf(a.w, w.y, acc[3][1]);
            acc[3][2] = fmaf(a.w, w.z, acc[3][2]); acc[3][3] = fmaf(a.w, w.w, acc[3][3]);
        }
    }

#pragma unroll
    for (int i = 0; i < 4; i++) {
        float4 o;
        float r[4];
#pragma unroll
        for (int j = 0; j < 4; j++) {
            float v = acc[i][j];
            if (EPI == 1) {
                v += bias[n0 + tx * 4 + j];
                v = fmaxf(v, 0.f) + log1pf(expf(-fabsf(v)));   // softplus, stable
            }
            r[j] = v;
        }
        o.x = r[0]; o.y = r[1]; o.z = r[2]; o.w = r[3];
        *(float4*)&C[(size_t)(m0 + ty * 4 + i) * N + n0 + tx * 4] = o;
    }
}

// ---------------- packed-bf16x3 MFMA GEMM: C[M][N] = A[M][K(lda)] * W[N][K]^T ----------------
// BM=128, 256 threads (4 waves). BN=128: waves 2x2 (64x64); BN=64: waves 4x1 (32x64).
// EPI: 0 = fp32 C only; 2 = fp32 C + packed PC.
template<int BN, int EPI>
__global__ __launch_bounds__(256) void gemm_mfma_p(
    const uint* __restrict__ PA, int lda,
    const uint* __restrict__ PW,
    float* __restrict__ C, uint* __restrict__ PC, int N, int K)
{
    constexpr int MR = (BN == 128) ? 4 : 2;
    constexpr int NR = 4;
    const int m0 = blockIdx.x * 128;
    const int n0 = blockIdx.y * BN;
    const int tid = threadIdx.x;
    const int wid = tid >> 6;
    const int lane = tid & 63;
    const int rb = (BN == 128) ? (wid >> 1) * 64 : wid * 32;
    const int cb = (BN == 128) ? (wid & 1) * 64 : 0;
    const int lr = lane & 15;
    const int lk = (lane >> 4) * 8;

    __shared__ alignas(16) ushort Ah[128][40], Al[128][40];
    __shared__ alignas(16) ushort Bh[BN][40],  Bl[BN][40];

    f32x4 acc[MR][NR];
#pragma unroll
    for (int m = 0; m < MR; m++)
#pragma unroll
        for (int n = 0; n < NR; n++) acc[m][n] = (f32x4){0.f, 0.f, 0.f, 0.f};

    const int srow = tid >> 3;        // 0..31
    const int scol = (tid & 7) * 4;   // 0,4,...,28

    for (int k0 = 0; k0 < K; k0 += 32) {
        uint4 av[4], wv[BN / 32];
#pragma unroll
        for (int i = 0; i < 4; i++)
            av[i] = *(const uint4*)&PA[(size_t)(m0 + srow + 32 * i) * lda + k0 + scol];
#pragma unroll
        for (int i = 0; i < BN / 32; i++)
            wv[i] = *(const uint4*)&PW[(size_t)(n0 + srow + 32 * i) * K + k0 + scol];

        __syncthreads();
#pragma unroll
        for (int i = 0; i < 4; i++)
            unp4(av[i], &Ah[srow + 32 * i][scol], &Al[srow + 32 * i][scol]);
#pragma unroll
        for (int i = 0; i < BN / 32; i++)
            unp4(wv[i], &Bh[srow + 32 * i][scol], &Bl[srow + 32 * i][scol]);
        __syncthreads();

        s8v ah[MR], al[MR], bh[NR], bl[NR];
#pragma unroll
        for (int m = 0; m < MR; m++) {
            ah[m] = *(const s8v*)&Ah[rb + m * 16 + lr][lk];
            al[m] = *(const s8v*)&Al[rb + m * 16 + lr][lk];
        }
#pragma unroll
        for (int n = 0; n < NR; n++) {
            bh[n] = *(const s8v*)&Bh[cb + n * 16 + lr][lk];
            bl[n] = *(const s8v*)&Bl[cb + n * 16 + lr][lk];
        }
#pragma unroll
        for (int m = 0; m < MR; m++)
#pragma unroll
            for (int n = 0; n < NR; n++) {
                acc[m][n] = __builtin_amdgcn_mfma_f32_16x16x32_bf16(ah[m], bh[n], acc[m][n], 0, 0, 0);
                acc[m][n] = __builtin_amdgcn_mfma_f32_16x16x32_bf16(ah[m], bl[n], acc[m][n], 0, 0, 0);
                acc[m][n] = __builtin_amdgcn_mfma_f32_16x16x32_bf16(al[m], bh[n], acc[m][n], 0, 0, 0);
            }
    }

    // C/D layout: col = lane&15, row = (lane>>4)*4 + reg
#pragma unroll
    for (int m = 0; m < MR; m++)
#pragma unroll
        for (int n = 0; n < NR; n++) {
#pragma unroll
            for (int r = 0; r < 4; r++) {
                int grow = m0 + rb + m * 16 + (lane >> 4) * 4 + r;
                int gcol = n0 + cb + n * 16 + lr;
                float v = acc[m][n][r];
                C[(size_t)grow * N + gcol] = v;
                if (EPI == 2) PC[(size_t)grow * N + gcol] = packbf(v);
            }
        }
}

// ---------------- depthwise causal conv(4) + silu; fp32 + packed out ----------------
__global__ void dwconv_silu_kernel(const float* __restrict__ xz, const float* __restrict__ cw,
                                   const float* __restrict__ cb, float* __restrict__ xc,
                                   uint* __restrict__ pxc) {
    int idx = blockIdx.x * 256 + threadIdx.x;   // over MROWS*DI
    int d = idx & (DI - 1);
    int r = idx >> 10;                          // row = b*L + t
    int tl = r & (LSEQ - 1);
    float acc = cb[d];
#pragma unroll
    for (int k = 0; k < DCONVN; k++) {
        int ts = tl - 3 + k;
        if (ts >= 0) acc = fmaf(xz[(size_t)(r - 3 + k) * (2 * DI) + d], cw[d * DCONVN + k], acc);
    }
    float sig = 1.f / (1.f + expf(-acc));
    float v = acc * sig;
    xc[idx] = v;
    pxc[idx] = packbf(v);
}

// ---------------- chunked selective scan ----------------
__global__ __launch_bounds__(256) void scan_local_kernel(
    const float* __restrict__ dt, const float* __restrict__ xc,
    const float* __restrict__ dbc, const float* __restrict__ A_log,
    float* __restrict__ S, float* __restrict__ P)
{
    int s    = threadIdx.x & 15;
    int dl   = threadIdx.x >> 4;
    int dblk = blockIdx.x & 63;
    int c    = (blockIdx.x >> 6) & (NCHUNK - 1);
    int b    = blockIdx.x >> 10;           // /(64*NCHUNK)
    int d    = dblk * 16 + dl;

    float Aval = -expf(A_log[d * DSTATE + s]);
    float h = 0.f, sumdt = 0.f;
    int rowbase = b * LSEQ + c * SCHUNK;

#pragma unroll 4
    for (int t = 0; t < SCHUNK; t++) {
        int r = rowbase + t;
        float dtv = dt[(size_t)r * DI + d];
        float xcv = xc[(size_t)r * DI + d];
        float Bv  = dbc[(size_t)r * 64 + DTRANK + s];
        float e = expf(dtv * Aval);
        h = fmaf(e, h, dtv * xcv * Bv);
        sumdt += dtv;
    }
    size_t idx = ((size_t)(b * NCHUNK + c) * DI + d) * DSTATE + s;
    S[idx] = h;
    P[idx] = expf(Aval * sumdt);    // product of per-step exp factors
}

__global__ __launch_bounds__(256) void scan_combine_kernel(
    const float* __restrict__ S, const float* __restrict__ P, float* __restrict__ H)
{
    int idx = blockIdx.x * 256 + threadIdx.x;    // over B*DI*DSTATE = 32768
    int b = idx >> 14;
    int rem = idx & 16383;                        // d*16+s
    float h = 0.f;
#pragma unroll
    for (int c = 0; c < NCHUNK; c++) {
        size_t off = ((size_t)(b * NCHUNK + c) * DI) * DSTATE + rem;
        H[off] = h;
        h = fmaf(P[off], h, S[off]);
    }
}

__global__ __launch_bounds__(256) void scan_out_kernel(
    const float* __restrict__ dt, const float* __restrict__ xc,
    const float* __restrict__ dbc, const float* __restrict__ xz,
    const float* __restrict__ A_log, const float* __restrict__ Dp,
    const float* __restrict__ H, uint* __restrict__ py)
{
    int s    = threadIdx.x & 15;
    int dl   = threadIdx.x >> 4;
    int dblk = blockIdx.x & 63;
    int c    = (blockIdx.x >> 6) & (NCHUNK - 1);
    int b    = blockIdx.x >> 10;
    int d    = dblk * 16 + dl;

    float Aval = -expf(A_log[d * DSTATE + s]);
    float Dval = Dp[d];
    float h = H[((size_t)(b * NCHUNK + c) * DI + d) * DSTATE + s];
    int rowbase = b * LSEQ + c * SCHUNK;

    for (int t = 0; t < SCHUNK; t++) {
        int r = rowbase + t;
        float dtv = dt[(size_t)r * DI + d];
        float xcv = xc[(size_t)r * DI + d];
        float Bv  = dbc[(size_t)r * 64 + DTRANK + s];
        float Cv  = dbc[(size_t)r * 64 + DTRANK + DSTATE + s];
        float e = expf(dtv * Aval);
        h = fmaf(e, h, dtv * xcv * Bv);
        float p = h * Cv;
        p += __shfl_xor(p, 1); p += __shfl_xor(p, 2);
        p += __shfl_xor(p, 4); p += __shfl_xor(p, 8);
        if (s == 0) {
            float zv = xz[(size_t)r * (2 * DI) + DI + d];
            float zsig = 1.f / (1.f + expf(-zv));
            py[(size_t)r * DI + d] = packbf((p + Dval * xcv) * (zv * zsig));
        }
    }
}

// ---------------- final FC: (B,512) @ fc_w(256,512)^T + fc_b ----------------
__global__ void fc_kernel(const float* __restrict__ x, const float* __restrict__ fcw,
                          const float* __restrict__ fcb, float* __restrict__ out) {
    int b = blockIdx.x;
    int v = threadIdx.x;   // 0..255
    __shared__ float rep[DM];
    const float* xr = x + (size_t)(b * LSEQ + LSEQ - 1) * DM;
    for (int i = threadIdx.x; i < DM; i += 256) rep[i] = xr[i];
    __syncthreads();
    float acc = fcb[v];
    for (int k = 0; k < DM; k++) acc = fmaf(rep[k], fcw[v * DM + k], acc);
    out[b * VOCABN + v] = acc;
}

extern "C" void kernel_launch(void* const* d_in, const int* in_sizes, int n_in,
                              void* d_out, int out_size, void* d_ws, size_t ws_size,
                              hipStream_t stream) {
    const int*   tokens    = (const int*)  d_in[0];
    const float* emb       = (const float*)d_in[1];
    const float* conv1_w   = (const float*)d_in[2];
    const float* conv1_b   = (const float*)d_in[3];
    const float* ln1_g     = (const float*)d_in[4];
    const float* ln1_b     = (const float*)d_in[5];
    const float* conv2_w   = (const float*)d_in[6];
    const float* conv2_b   = (const float*)d_in[7];
    const float* ln2_g     = (const float*)d_in[8];
    const float* ln2_b     = (const float*)d_in[9];
    const float* pos_emb   = (const float*)d_in[10];
    const float* in_proj_w = (const float*)d_in[11];
    const float* conv_w    = (const float*)d_in[12];
    const float* conv_b    = (const float*)d_in[13];
    const float* x_proj_w  = (const float*)d_in[14];
    const float* dt_proj_w = (const float*)d_in[15];
    const float* dt_proj_b = (const float*)d_in[16];
    const float* A_log     = (const float*)d_in[17];
    const float* Dp_all    = (const float*)d_in[18];
    const float* out_proj_w= (const float*)d_in[19];
    const float* fc_w      = (const float*)d_in[20];
    const float* fc_b      = (const float*)d_in[21];

    float* ws = (float*)d_ws;
    float* X    = ws;                          // (B,L,512) fp32 (fc input)
    float* T1   = X   + 2097152;               // fp32 frontend tmp; then scan S/P/H
    float* XZ   = T1  + 2097152;               // (B,L,2048) fp32
    float* XC   = XZ  + 8388608;               // (B,L,1024) fp32
    float* DT   = XC  + 4194304;               // (B,L,1024) fp32
    uint*  PY   = (uint*)(DT + 4194304);       // (B,L,1024) packed
    float* DBC  = (float*)PY + 4194304;        // (B,L,64) fp32
    uint*  PX   = (uint*)(DBC + 262144);       // (B,L,512) packed
    uint*  PXC  = PX  + 2097152;               // (B,L,1024) packed
    uint*  PWIN = PXC + 4194304;               // 2048x512 packed (per-layer)
    uint*  PWOUT= PWIN + 1048576;              // 512x1024 packed
    uint*  PWX  = PWOUT + 524288;              // 64x1024 packed
    // aliases (disjoint lifetimes):
    uint*  PX0  = (uint*)XZ;                   // (B,L,384) packed, pre-mamba only
    uint*  PWC1 = (uint*)XC;                   // [5][512][384] packed, frontend only
    uint*  PWC2 = (uint*)XC + 983040;          // [3][512][512] packed, frontend only
    uint*  PB   = (uint*)DT;                   // (B,L,512) packed ln1 out, frontend only
    float* SCN_S = T1;
    float* SCN_P = T1 + 524288;
    float* SCN_H = T1 + 1048576;

    // frontend
    pack_convw_kernel<EMBN, 5><<<(512 * EMBN * 5 + 255) / 256, 256, 0, stream>>>(conv1_w, PWC1);
    pack_convw_kernel<DM,   3><<<(512 * DM   * 3 + 255) / 256, 256, 0, stream>>>(conv2_w, PWC2);
    embed_kernel<<<(MROWS * EMBN) / 256, 256, 0, stream>>>(tokens, emb, PX0);
    conv_mfma_kernel<EMBN, 5, 2><<<dim3(MROWS / 128, 16), 256, 0, stream>>>(PX0, PWC1, conv1_b, T1);
    ln_kernel<false, true><<<MROWS / 4, 256, 0, stream>>>(T1, ln1_g, ln1_b, nullptr, nullptr, PB);
    conv_mfma_kernel<DM, 3, 1><<<dim3(MROWS / 128, 16), 256, 0, stream>>>(PB, PWC2, conv2_b, T1);
    ln_kernel<true, true><<<MROWS / 4, 256, 0, stream>>>(T1, ln2_g, ln2_b, pos_emb, nullptr, PX);

    // mamba layers
    for (int l = 0; l < NLAYER; l++) {
        pack3_kernel<<<(2 * DI * DM + DM * DI + 64 * DI + 255) / 256, 256, 0, stream>>>(
            in_proj_w + (size_t)l * 2 * DI * DM, 2 * DI * DM,
            out_proj_w + (size_t)l * DM * DI, DM * DI,
            x_proj_w + (size_t)l * 64 * DI, 64 * DI,
            PWIN, PWOUT, PWX);
        gemm_mfma_p<128, 0><<<dim3(MROWS / 128, (2 * DI) / 128), 256, 0, stream>>>(
            PX, DM, PWIN, XZ, nullptr, 2 * DI, DM);
        dwconv_silu_kernel<<<(MROWS * DI) / 256, 256, 0, stream>>>(
            XZ, conv_w + (size_t)l * DI * DCONVN, conv_b + (size_t)l * DI, XC, PXC);
        gemm_mfma_p<64, 0><<<dim3(MROWS / 128, 1), 256, 0, stream>>>(
            PXC, DI, PWX, DBC, nullptr, 64, DI);
        gemm_kernel<1><<<dim3(MROWS / 64, DI / 64), 256, 0, stream>>>(
            DBC, 64, dt_proj_w + (size_t)l * DI * DTRANK, dt_proj_b + (size_t)l * DI, DT, DI, DTRANK);
        scan_local_kernel<<<BBATCH * NCHUNK * (DI / 16), 256, 0, stream>>>(
            DT, XC, DBC, A_log + (size_t)l * DI * DSTATE, SCN_S, SCN_P);
        scan_combine_kernel<<<(BBATCH * DI * DSTATE) / 256, 256, 0, stream>>>(
            SCN_S, SCN_P, SCN_H);
        scan_out_kernel<<<BBATCH * NCHUNK * (DI / 16), 256, 0, stream>>>(
            DT, XC, DBC, XZ, A_log + (size_t)l * DI * DSTATE, Dp_all + (size_t)l * DI,
            SCN_H, PY);
        gemm_mfma_p<64, 2><<<dim3(MROWS / 128, DM / 64), 256, 0, stream>>>(
            PY, DI, PWOUT, X, PX, DM, DI);
    }

    fc_kernel<<<BBATCH, 256, 0, stream>>>(X, fc_w, fc_b, (float*)d_out);
}

// Round 6
// 2128.888 us; speedup vs baseline: 7.2557x; 1.2993x over previous
//
#include <hip/hip_runtime.h>
#include <hip/hip_bf16.h>
#include <math.h>

#define VOCABN 256
#define EMBN   384
#define DM     512
#define DI     1024
#define DSTATE 16
#define DCONVN 4
#define DTRANK 32
#define NLAYER 8
#define BBATCH 2
#define LSEQ   2048
#define MROWS  (BBATCH*LSEQ)   // 4096
#define SCHUNK 64
#define NCHUNK (LSEQ/SCHUNK)   // 32

typedef short s8v  __attribute__((ext_vector_type(8)));
typedef float f32x4 __attribute__((ext_vector_type(4)));

// ---------------- bf16 split/pack helpers ----------------
__device__ __forceinline__ ushort f2bf(float f) {
    uint u = __float_as_uint(f);
    return (ushort)((u + 0x7fffu + ((u >> 16) & 1u)) >> 16);
}
__device__ __forceinline__ float bf2f(ushort h) {
    return __uint_as_float((uint)h << 16);
}
// packed element: hi bf16 in high 16 bits, lo bf16 (residual) in low 16 bits
__device__ __forceinline__ uint packbf(float f) {
    ushort h = f2bf(f);
    ushort l = f2bf(f - bf2f(h));
    return ((uint)h << 16) | (uint)l;
}
__device__ __forceinline__ void unp4(uint4 p, ushort* hdst, ushort* ldst) {
    ushort4 h, l;
    h.x = (ushort)(p.x >> 16); l.x = (ushort)(p.x & 0xffffu);
    h.y = (ushort)(p.y >> 16); l.y = (ushort)(p.y & 0xffffu);
    h.z = (ushort)(p.z >> 16); l.z = (ushort)(p.z & 0xffffu);
    h.w = (ushort)(p.w >> 16); l.w = (ushort)(p.w & 0xffffu);
    *(ushort4*)hdst = h; *(ushort4*)ldst = l;
}

// ---------------- pack kernels ----------------
__global__ void pack3_kernel(const float* __restrict__ a, int na,
                             const float* __restrict__ b, int nb,
                             const float* __restrict__ c, int nc,
                             uint* __restrict__ pa, uint* __restrict__ pb, uint* __restrict__ pc) {
    int i = blockIdx.x * 256 + threadIdx.x;
    if (i < na) pa[i] = packbf(a[i]);
    else if (i < na + nb) pb[i - na] = packbf(b[i - na]);
    else if (i < na + nb + nc) pc[i - na - nb] = packbf(c[i - na - nb]);
}

// conv weights: w[co][ci][k] fp32 -> pw[k][co][ci] packed
template<int CI, int CK>
__global__ void pack_convw_kernel(const float* __restrict__ w, uint* __restrict__ pw) {
    int idx = blockIdx.x * 256 + threadIdx.x;
    if (idx >= 512 * CI * CK) return;
    int k  = idx % CK;
    int ci = (idx / CK) % CI;
    int co = idx / (CK * CI);
    pw[((size_t)(k * 512) + co) * CI + ci] = packbf(w[idx]);
}

// ---------------- embedding gather -> packed ----------------
__global__ void embed_kernel(const int* __restrict__ tok, const float* __restrict__ emb,
                             uint* __restrict__ px0) {
    int idx = blockIdx.x * 256 + threadIdx.x;   // over MROWS*EMBN
    int c = idx % EMBN;
    int t = idx / EMBN;
    px0[idx] = packbf(emb[tok[t] * EMBN + c]);
}

__device__ __forceinline__ float gelu_exact(float x) {
    return 0.5f * x * (1.f + erff(x * 0.70710678118654752f));
}

// ---------------- conv as implicit-GEMM MFMA (bf16x3) ----------------
template<int CI, int CK, int PAD>
__global__ __launch_bounds__(256) void conv_mfma_kernel(
    const uint* __restrict__ PA, const uint* __restrict__ PW,
    const float* __restrict__ bias, float* __restrict__ out)
{
    constexpr int ROWS = 128 + CK - 1;
    const int t0  = blockIdx.x * 128;
    const int co0 = blockIdx.y * 32;
    const int tid = threadIdx.x;
    const int wid = tid >> 6, lane = tid & 63;
    const int rb = wid * 32;
    const int lr = lane & 15, lk = (lane >> 4) * 8;
    const int bstart = (t0 / LSEQ) * LSEQ;

    __shared__ alignas(16) ushort Ah[ROWS][40], Al[ROWS][40];
    __shared__ alignas(16) ushort Bh[CK][32][40], Bl[CK][32][40];

    f32x4 acc[2][2];
#pragma unroll
    for (int m = 0; m < 2; m++)
#pragma unroll
        for (int n = 0; n < 2; n++) acc[m][n] = (f32x4){0.f, 0.f, 0.f, 0.f};

    for (int ci0 = 0; ci0 < CI; ci0 += 32) {
        __syncthreads();
        for (int idx = tid; idx < ROWS * 8; idx += 256) {
            int r = idx >> 3, c4 = (idx & 7) * 4;
            int g = t0 - PAD + r;
            uint4 v = make_uint4(0u, 0u, 0u, 0u);
            if (g >= bstart && g < bstart + LSEQ)
                v = *(const uint4*)&PA[(size_t)g * CI + ci0 + c4];
            unp4(v, &Ah[r][c4], &Al[r][c4]);
        }
        for (int idx = tid; idx < CK * 32 * 8; idx += 256) {
            int k = idx >> 8;
            int r = (idx >> 3) & 31;
            int c4 = (idx & 7) * 4;
            uint4 v = *(const uint4*)&PW[((size_t)(k * 512) + co0 + r) * CI + ci0 + c4];
            unp4(v, &Bh[k][r][c4], &Bl[k][r][c4]);
        }
        __syncthreads();

#pragma unroll
        for (int k = 0; k < CK; k++) {
            s8v ah[2], al[2], bh[2], bl[2];
#pragma unroll
            for (int m = 0; m < 2; m++) {
                ah[m] = *(const s8v*)&Ah[rb + m * 16 + lr + k][lk];
                al[m] = *(const s8v*)&Al[rb + m * 16 + lr + k][lk];
            }
#pragma unroll
            for (int n = 0; n < 2; n++) {
                bh[n] = *(const s8v*)&Bh[k][n * 16 + lr][lk];
                bl[n] = *(const s8v*)&Bl[k][n * 16 + lr][lk];
            }
#pragma unroll
            for (int m = 0; m < 2; m++)
#pragma unroll
                for (int n = 0; n < 2; n++) {
                    acc[m][n] = __builtin_amdgcn_mfma_f32_16x16x32_bf16(ah[m], bh[n], acc[m][n], 0, 0, 0);
                    acc[m][n] = __builtin_amdgcn_mfma_f32_16x16x32_bf16(ah[m], bl[n], acc[m][n], 0, 0, 0);
                    acc[m][n] = __builtin_amdgcn_mfma_f32_16x16x32_bf16(al[m], bh[n], acc[m][n], 0, 0, 0);
                }
        }
    }

#pragma unroll
    for (int m = 0; m < 2; m++)
#pragma unroll
        for (int n = 0; n < 2; n++) {
            int gcol = co0 + n * 16 + lr;
            float bv = bias[gcol];
#pragma unroll
            for (int r = 0; r < 4; r++) {
                int grow = t0 + rb + m * 16 + (lane >> 4) * 4 + r;
                out[(size_t)grow * 512 + gcol] = gelu_exact(acc[m][n][r] + bv);
            }
        }
}

// ---------------- layernorm over 512, optional +pos_emb; packed or fp32 out ----------------
template<bool ADDPOS, bool PACK>
__global__ __launch_bounds__(256) void ln_kernel(
    const float* __restrict__ in, const float* __restrict__ g, const float* __restrict__ bb,
    const float* __restrict__ pos, float* __restrict__ out, uint* __restrict__ pout)
{
    int row  = blockIdx.x * 4 + (threadIdx.x >> 6);
    int lane = threadIdx.x & 63;
    const float* xr = in + (size_t)row * DM;
    float v[8];
    float s = 0.f;
#pragma unroll
    for (int i = 0; i < 8; i++) { v[i] = xr[lane + i * 64]; s += v[i]; }
#pragma unroll
    for (int o = 32; o >= 1; o >>= 1) s += __shfl_xor(s, o);
    float mu = s * (1.f / 512.f);
    float var = 0.f;
#pragma unroll
    for (int i = 0; i < 8; i++) { float d = v[i] - mu; var = fmaf(d, d, var); }
#pragma unroll
    for (int o = 32; o >= 1; o >>= 1) var += __shfl_xor(var, o);
    var *= (1.f / 512.f);
    float rstd = rsqrtf(var + 1e-5f);
    int t = row & (LSEQ - 1);
#pragma unroll
    for (int i = 0; i < 8; i++) {
        int c = lane + i * 64;
        float o = (v[i] - mu) * rstd * g[c] + bb[c];
        if (ADDPOS) o += pos[t * DM + c];
        if (PACK) pout[(size_t)row * DM + c] = packbf(o);
        else      out [(size_t)row * DM + c] = o;
    }
}

// ---------------- fp32 GEMM (kept for dt_proj, K=32) ----------------
template<int EPI>
__global__ __launch_bounds__(256) void gemm_kernel(
    const float* __restrict__ A, int lda,
    const float* __restrict__ Wm,
    const float* __restrict__ bias,
    float* __restrict__ C, int N, int K)
{
    const int m0 = blockIdx.x * 64;
    const int n0 = blockIdx.y * 64;
    const int tid = threadIdx.x;
    const int tx = tid & 15, ty = tid >> 4;

    __shared__ float As[16][64];
    __shared__ float Ws[16][64];

    float acc[4][4];
#pragma unroll
    for (int i = 0; i < 4; i++)
#pragma unroll
        for (int j = 0; j < 4; j++) acc[i][j] = 0.f;

    const int am = tid >> 2;          // 0..63
    const int ak = (tid & 3) * 4;     // 0,4,8,12

    for (int k0 = 0; k0 < K; k0 += 16) {
        float4 av = *(const float4*)&A[(size_t)(m0 + am) * lda + k0 + ak];
        float4 wv = *(const float4*)&Wm[(size_t)(n0 + am) * K + k0 + ak];
        __syncthreads();
        As[ak + 0][am] = av.x; As[ak + 1][am] = av.y; As[ak + 2][am] = av.z; As[ak + 3][am] = av.w;
        Ws[ak + 0][am] = wv.x; Ws[ak + 1][am] = wv.y; Ws[ak + 2][am] = wv.z; Ws[ak + 3][am] = wv.w;
        __syncthreads();
#pragma unroll
        for (int kk = 0; kk < 16; kk++) {
            float4 a = *(const float4*)&As[kk][ty * 4];
            float4 w = *(const float4*)&Ws[kk][tx * 4];
            acc[0][0] = fmaf(a.x, w.x, acc[0][0]); acc[0][1] = fmaf(a.x, w.y, acc[0][1]);
            acc[0][2] = fmaf(a.x, w.z, acc[0][2]); acc[0][3] = fmaf(a.x, w.w, acc[0][3]);
            acc[1][0] = fmaf(a.y, w.x, acc[1][0]); acc[1][1] = fmaf(a.y, w.y, acc[1][1]);
            acc[1][2] = fmaf(a.y, w.z, acc[1][2]); acc[1][3] = fmaf(a.y, w.w, acc[1][3]);
            acc[2][0] = fmaf(a.z, w.x, acc[2][0]); acc[2][1] = fmaf(a.z, w.y, acc[2][1]);
            acc[2][2] = fmaf(a.z, w.z, acc[2][2]); acc[2][3] = fmaf(a.z, w.w, acc[2][3]);
            acc[3][0] = fmaf(a.w, w.x, acc[3][0]); acc[3][1] = fmaf(a.w, w.y, acc[3][1]);
            acc[3][2] = fmaf(a.w, w.z, acc[3][2]); acc[3][3] = fmaf(a.w, w.w, acc[3][3]);
        }
    }

#pragma unroll
    for (int i = 0; i < 4; i++) {
        float4 o;
        float r[4];
#pragma unroll
        for (int j = 0; j < 4; j++) {
            float v = acc[i][j];
            if (EPI == 1) {
                v += bias[n0 + tx * 4 + j];
                v = fmaxf(v, 0.f) + log1pf(expf(-fabsf(v)));   // softplus, stable
            }
            r[j] = v;
        }
        o.x = r[0]; o.y = r[1]; o.z = r[2]; o.w = r[3];
        *(float4*)&C[(size_t)(m0 + ty * 4 + i) * N + n0 + tx * 4] = o;
    }
}

// ---------------- packed-bf16x3 MFMA GEMM ----------------
template<int BN, int EPI>
__global__ __launch_bounds__(256) void gemm_mfma_p(
    const uint* __restrict__ PA, int lda,
    const uint* __restrict__ PW,
    float* __restrict__ C, uint* __restrict__ PC, int N, int K)
{
    constexpr int MR = (BN == 128) ? 4 : 2;
    constexpr int NR = 4;
    const int m0 = blockIdx.x * 128;
    const int n0 = blockIdx.y * BN;
    const int tid = threadIdx.x;
    const int wid = tid >> 6;
    const int lane = tid & 63;
    const int rb = (BN == 128) ? (wid >> 1) * 64 : wid * 32;
    const int cb = (BN == 128) ? (wid & 1) * 64 : 0;
    const int lr = lane & 15;
    const int lk = (lane >> 4) * 8;

    __shared__ alignas(16) ushort Ah[128][40], Al[128][40];
    __shared__ alignas(16) ushort Bh[BN][40],  Bl[BN][40];

    f32x4 acc[MR][NR];
#pragma unroll
    for (int m = 0; m < MR; m++)
#pragma unroll
        for (int n = 0; n < NR; n++) acc[m][n] = (f32x4){0.f, 0.f, 0.f, 0.f};

    const int srow = tid >> 3;        // 0..31
    const int scol = (tid & 7) * 4;   // 0,4,...,28

    for (int k0 = 0; k0 < K; k0 += 32) {
        uint4 av[4], wv[BN / 32];
#pragma unroll
        for (int i = 0; i < 4; i++)
            av[i] = *(const uint4*)&PA[(size_t)(m0 + srow + 32 * i) * lda + k0 + scol];
#pragma unroll
        for (int i = 0; i < BN / 32; i++)
            wv[i] = *(const uint4*)&PW[(size_t)(n0 + srow + 32 * i) * K + k0 + scol];

        __syncthreads();
#pragma unroll
        for (int i = 0; i < 4; i++)
            unp4(av[i], &Ah[srow + 32 * i][scol], &Al[srow + 32 * i][scol]);
#pragma unroll
        for (int i = 0; i < BN / 32; i++)
            unp4(wv[i], &Bh[srow + 32 * i][scol], &Bl[srow + 32 * i][scol]);
        __syncthreads();

        s8v ah[MR], al[MR], bh[NR], bl[NR];
#pragma unroll
        for (int m = 0; m < MR; m++) {
            ah[m] = *(const s8v*)&Ah[rb + m * 16 + lr][lk];
            al[m] = *(const s8v*)&Al[rb + m * 16 + lr][lk];
        }
#pragma unroll
        for (int n = 0; n < NR; n++) {
            bh[n] = *(const s8v*)&Bh[cb + n * 16 + lr][lk];
            bl[n] = *(const s8v*)&Bl[cb + n * 16 + lr][lk];
        }
#pragma unroll
        for (int m = 0; m < MR; m++)
#pragma unroll
            for (int n = 0; n < NR; n++) {
                acc[m][n] = __builtin_amdgcn_mfma_f32_16x16x32_bf16(ah[m], bh[n], acc[m][n], 0, 0, 0);
                acc[m][n] = __builtin_amdgcn_mfma_f32_16x16x32_bf16(ah[m], bl[n], acc[m][n], 0, 0, 0);
                acc[m][n] = __builtin_amdgcn_mfma_f32_16x16x32_bf16(al[m], bh[n], acc[m][n], 0, 0, 0);
            }
    }

#pragma unroll
    for (int m = 0; m < MR; m++)
#pragma unroll
        for (int n = 0; n < NR; n++) {
#pragma unroll
            for (int r = 0; r < 4; r++) {
                int grow = m0 + rb + m * 16 + (lane >> 4) * 4 + r;
                int gcol = n0 + cb + n * 16 + lr;
                float v = acc[m][n][r];
                C[(size_t)grow * N + gcol] = v;
                if (EPI == 2) PC[(size_t)grow * N + gcol] = packbf(v);
            }
        }
}

// ---------------- depthwise causal conv(4) + silu; fp32 + packed out ----------------
__global__ void dwconv_silu_kernel(const float* __restrict__ xz, const float* __restrict__ cw,
                                   const float* __restrict__ cb, float* __restrict__ xc,
                                   uint* __restrict__ pxc) {
    int idx = blockIdx.x * 256 + threadIdx.x;   // over MROWS*DI
    int d = idx & (DI - 1);
    int r = idx >> 10;                          // row = b*L + t
    int tl = r & (LSEQ - 1);
    float acc = cb[d];
#pragma unroll
    for (int k = 0; k < DCONVN; k++) {
        int ts = tl - 3 + k;
        if (ts >= 0) acc = fmaf(xz[(size_t)(r - 3 + k) * (2 * DI) + d], cw[d * DCONVN + k], acc);
    }
    float sig = 1.f / (1.f + expf(-acc));
    float v = acc * sig;
    xc[idx] = v;
    pxc[idx] = packbf(v);
}

// ---------------- chunked selective scan, 4-states-per-thread ----------------
// thread = (d, sg): sg = tid&3 owns states s = sg*4..sg*4+3 in registers.
// block = 256 thr (64 d x 4 sg). grid = 16 dq x NCHUNK x B.
__global__ __launch_bounds__(256) void scan_local_kernel(
    const float* __restrict__ dt, const float* __restrict__ xc,
    const float* __restrict__ dbc, const float* __restrict__ A_log,
    float* __restrict__ S, float* __restrict__ P)
{
    const int sg = threadIdx.x & 3;
    const int dl = threadIdx.x >> 2;           // 0..63
    const int dq = blockIdx.x & 15;
    const int c  = (blockIdx.x >> 4) & (NCHUNK - 1);
    const int b  = blockIdx.x >> 9;            // 16*32=512 blocks per batch
    const int d  = dq * 64 + dl;

    float4 alog = *(const float4*)&A_log[d * DSTATE + sg * 4];
    float Av[4]; // -exp(A_log) * log2(e), pre-folded for exp2f
    Av[0] = -expf(alog.x) * 1.44269504f;
    Av[1] = -expf(alog.y) * 1.44269504f;
    Av[2] = -expf(alog.z) * 1.44269504f;
    Av[3] = -expf(alog.w) * 1.44269504f;

    float h[4] = {0.f, 0.f, 0.f, 0.f};
    float sumdt = 0.f;
    const int rowbase = b * LSEQ + c * SCHUNK;

#pragma unroll 4
    for (int t = 0; t < SCHUNK; t++) {
        int r = rowbase + t;
        float dtv = dt[(size_t)r * DI + d];
        float xcv = xc[(size_t)r * DI + d];
        float4 Bv = *(const float4*)&dbc[(size_t)r * 64 + DTRANK + sg * 4];
        float dx = dtv * xcv;
        h[0] = fmaf(exp2f(dtv * Av[0]), h[0], dx * Bv.x);
        h[1] = fmaf(exp2f(dtv * Av[1]), h[1], dx * Bv.y);
        h[2] = fmaf(exp2f(dtv * Av[2]), h[2], dx * Bv.z);
        h[3] = fmaf(exp2f(dtv * Av[3]), h[3], dx * Bv.w);
        sumdt += dtv;
    }
    size_t off = ((size_t)(b * NCHUNK + c) * DI + d) * DSTATE + sg * 4;
    *(float4*)&S[off] = make_float4(h[0], h[1], h[2], h[3]);
    *(float4*)&P[off] = make_float4(exp2f(Av[0] * sumdt), exp2f(Av[1] * sumdt),
                                    exp2f(Av[2] * sumdt), exp2f(Av[3] * sumdt));
}

__global__ __launch_bounds__(256) void scan_combine_kernel(
    const float* __restrict__ S, const float* __restrict__ P, float* __restrict__ H)
{
    int idx = blockIdx.x * 256 + threadIdx.x;    // over B*DI*DSTATE = 32768
    int b = idx >> 14;
    int rem = idx & 16383;                        // d*16+s
    float h = 0.f;
#pragma unroll
    for (int c = 0; c < NCHUNK; c++) {
        size_t off = ((size_t)(b * NCHUNK + c) * DI) * DSTATE + rem;
        H[off] = h;
        h = fmaf(P[off], h, S[off]);
    }
}

__global__ __launch_bounds__(256) void scan_out_kernel(
    const float* __restrict__ dt, const float* __restrict__ xc,
    const float* __restrict__ dbc, const float* __restrict__ xz,
    const float* __restrict__ A_log, const float* __restrict__ Dp,
    const float* __restrict__ H, uint* __restrict__ py)
{
    const int sg = threadIdx.x & 3;
    const int dl = threadIdx.x >> 2;
    const int dq = blockIdx.x & 15;
    const int c  = (blockIdx.x >> 4) & (NCHUNK - 1);
    const int b  = blockIdx.x >> 9;
    const int d  = dq * 64 + dl;

    float4 alog = *(const float4*)&A_log[d * DSTATE + sg * 4];
    float Av[4];
    Av[0] = -expf(alog.x) * 1.44269504f;
    Av[1] = -expf(alog.y) * 1.44269504f;
    Av[2] = -expf(alog.z) * 1.44269504f;
    Av[3] = -expf(alog.w) * 1.44269504f;
    float Dval = Dp[d];

    float4 hv = *(const float4*)&H[((size_t)(b * NCHUNK + c) * DI + d) * DSTATE + sg * 4];
    float h[4] = {hv.x, hv.y, hv.z, hv.w};
    const int rowbase = b * LSEQ + c * SCHUNK;

#pragma unroll 2
    for (int t = 0; t < SCHUNK; t++) {
        int r = rowbase + t;
        float dtv = dt[(size_t)r * DI + d];
        float xcv = xc[(size_t)r * DI + d];
        float4 Bv = *(const float4*)&dbc[(size_t)r * 64 + DTRANK + sg * 4];
        float4 Cv = *(const float4*)&dbc[(size_t)r * 64 + DTRANK + DSTATE + sg * 4];
        float dx = dtv * xcv;
        h[0] = fmaf(exp2f(dtv * Av[0]), h[0], dx * Bv.x);
        h[1] = fmaf(exp2f(dtv * Av[1]), h[1], dx * Bv.y);
        h[2] = fmaf(exp2f(dtv * Av[2]), h[2], dx * Bv.z);
        h[3] = fmaf(exp2f(dtv * Av[3]), h[3], dx * Bv.w);
        float p = h[0] * Cv.x;
        p = fmaf(h[1], Cv.y, p);
        p = fmaf(h[2], Cv.z, p);
        p = fmaf(h[3], Cv.w, p);
        p += __shfl_xor(p, 1);
        p += __shfl_xor(p, 2);
        if (sg == 0) {
            float zv = xz[(size_t)r * (2 * DI) + DI + d];
            float zsig = 1.f / (1.f + exp2f(-zv * 1.44269504f));
            py[(size_t)r * DI + d] = packbf((p + Dval * xcv) * (zv * zsig));
        }
    }
}

// ---------------- final FC: (B,512) @ fc_w(256,512)^T + fc_b ----------------
__global__ void fc_kernel(const float* __restrict__ x, const float* __restrict__ fcw,
                          const float* __restrict__ fcb, float* __restrict__ out) {
    int b = blockIdx.x;
    int v = threadIdx.x;   // 0..255
    __shared__ float rep[DM];
    const float* xr = x + (size_t)(b * LSEQ + LSEQ - 1) * DM;
    for (int i = threadIdx.x; i < DM; i += 256) rep[i] = xr[i];
    __syncthreads();
    float acc = fcb[v];
    for (int k = 0; k < DM; k++) acc = fmaf(rep[k], fcw[v * DM + k], acc);
    out[b * VOCABN + v] = acc;
}

extern "C" void kernel_launch(void* const* d_in, const int* in_sizes, int n_in,
                              void* d_out, int out_size, void* d_ws, size_t ws_size,
                              hipStream_t stream) {
    const int*   tokens    = (const int*)  d_in[0];
    const float* emb       = (const float*)d_in[1];
    const float* conv1_w   = (const float*)d_in[2];
    const float* conv1_b   = (const float*)d_in[3];
    const float* ln1_g     = (const float*)d_in[4];
    const float* ln1_b     = (const float*)d_in[5];
    const float* conv2_w   = (const float*)d_in[6];
    const float* conv2_b   = (const float*)d_in[7];
    const float* ln2_g     = (const float*)d_in[8];
    const float* ln2_b     = (const float*)d_in[9];
    const float* pos_emb   = (const float*)d_in[10];
    const float* in_proj_w = (const float*)d_in[11];
    const float* conv_w    = (const float*)d_in[12];
    const float* conv_b    = (const float*)d_in[13];
    const float* x_proj_w  = (const float*)d_in[14];
    const float* dt_proj_w = (const float*)d_in[15];
    const float* dt_proj_b = (const float*)d_in[16];
    const float* A_log     = (const float*)d_in[17];
    const float* Dp_all    = (const float*)d_in[18];
    const float* out_proj_w= (const float*)d_in[19];
    const float* fc_w      = (const float*)d_in[20];
    const float* fc_b      = (const float*)d_in[21];

    float* ws = (float*)d_ws;
    float* X    = ws;                          // (B,L,512) fp32 (fc input)
    float* T1   = X   + 2097152;               // fp32 frontend tmp
    float* XZ   = T1  + 2097152;               // (B,L,2048) fp32
    float* XC   = XZ  + 8388608;               // (B,L,1024) fp32
    float* DT   = XC  + 4194304;               // (B,L,1024) fp32
    uint*  PY   = (uint*)(DT + 4194304);       // (B,L,1024) packed
    float* DBC  = (float*)PY + 4194304;        // (B,L,64) fp32
    uint*  PX   = (uint*)(DBC + 262144);       // (B,L,512) packed
    uint*  PXC  = PX  + 2097152;               // (B,L,1024) packed
    uint*  PWIN = PXC + 4194304;               // 2048x512 packed (per-layer)
    uint*  PWOUT= PWIN + 1048576;              // 512x1024 packed
    uint*  PWX  = PWOUT + 524288;              // 64x1024 packed
    // aliases (disjoint lifetimes):
    uint*  PX0  = (uint*)XZ;                   // (B,L,384) packed, pre-mamba only
    uint*  PWC1 = (uint*)XC;                   // frontend only
    uint*  PWC2 = (uint*)XC + 983040;          // frontend only
    uint*  PB   = (uint*)DT;                   // frontend only
    // scan chunk states alias PXC (dead after x_proj consumes it): 3 x 1,048,576
    float* SCN_S = (float*)PXC;
    float* SCN_P = SCN_S + 1048576;
    float* SCN_H = SCN_P + 1048576;

    // frontend
    pack_convw_kernel<EMBN, 5><<<(512 * EMBN * 5 + 255) / 256, 256, 0, stream>>>(conv1_w, PWC1);
    pack_convw_kernel<DM,   3><<<(512 * DM   * 3 + 255) / 256, 256, 0, stream>>>(conv2_w, PWC2);
    embed_kernel<<<(MROWS * EMBN) / 256, 256, 0, stream>>>(tokens, emb, PX0);
    conv_mfma_kernel<EMBN, 5, 2><<<dim3(MROWS / 128, 16), 256, 0, stream>>>(PX0, PWC1, conv1_b, T1);
    ln_kernel<false, true><<<MROWS / 4, 256, 0, stream>>>(T1, ln1_g, ln1_b, nullptr, nullptr, PB);
    conv_mfma_kernel<DM, 3, 1><<<dim3(MROWS / 128, 16), 256, 0, stream>>>(PB, PWC2, conv2_b, T1);
    ln_kernel<true, true><<<MROWS / 4, 256, 0, stream>>>(T1, ln2_g, ln2_b, pos_emb, nullptr, PX);

    // mamba layers
    for (int l = 0; l < NLAYER; l++) {
        pack3_kernel<<<(2 * DI * DM + DM * DI + 64 * DI + 255) / 256, 256, 0, stream>>>(
            in_proj_w + (size_t)l * 2 * DI * DM, 2 * DI * DM,
            out_proj_w + (size_t)l * DM * DI, DM * DI,
            x_proj_w + (size_t)l * 64 * DI, 64 * DI,
            PWIN, PWOUT, PWX);
        gemm_mfma_p<128, 0><<<dim3(MROWS / 128, (2 * DI) / 128), 256, 0, stream>>>(
            PX, DM, PWIN, XZ, nullptr, 2 * DI, DM);
        dwconv_silu_kernel<<<(MROWS * DI) / 256, 256, 0, stream>>>(
            XZ, conv_w + (size_t)l * DI * DCONVN, conv_b + (size_t)l * DI, XC, PXC);
        gemm_mfma_p<64, 0><<<dim3(MROWS / 128, 1), 256, 0, stream>>>(
            PXC, DI, PWX, DBC, nullptr, 64, DI);
        gemm_kernel<1><<<dim3(MROWS / 64, DI / 64), 256, 0, stream>>>(
            DBC, 64, dt_proj_w + (size_t)l * DI * DTRANK, dt_proj_b + (size_t)l * DI, DT, DI, DTRANK);
        scan_local_kernel<<<16 * NCHUNK * BBATCH, 256, 0, stream>>>(
            DT, XC, DBC, A_log + (size_t)l * DI * DSTATE, SCN_S, SCN_P);
        scan_combine_kernel<<<(BBATCH * DI * DSTATE) / 256, 256, 0, stream>>>(
            SCN_S, SCN_P, SCN_H);
        scan_out_kernel<<<16 * NCHUNK * BBATCH, 256, 0, stream>>>(
            DT, XC, DBC, XZ, A_log + (size_t)l * DI * DSTATE, Dp_all + (size_t)l * DI,
            SCN_H, PY);
        gemm_mfma_p<64, 2><<<dim3(MROWS / 128, DM / 64), 256, 0, stream>>>(
            PY, DI, PWOUT, X, PX, DM, DI);
    }

    fc_kernel<<<BBATCH, 256, 0, stream>>>(X, fc_w, fc_b, (float*)d_out);
}